// Round 7
// baseline (240.433 us; speedup 1.0000x reference)
//
#include <hip/hip_runtime.h>
#include <hip/hip_bf16.h>
#include <stdint.h>

#define DEVI static __device__ __forceinline__

typedef __attribute__((ext_vector_type(4))) float f32x4;
typedef __attribute__((ext_vector_type(8))) short bf16x8;
typedef unsigned short u16;
typedef unsigned int u32;
typedef unsigned long long u64;

// B=16, N=4096, C=384, H=8, D=48
#define BB 16
#define NN 4096
#define CC 384
#define HH 8
#define DD 48

DEVI u16 f2bf(float f) {
  union { float f; u32 u; } c; c.f = f;
  u32 u = c.u;
  u32 r = (u + 0x7FFFu + ((u >> 16) & 1u)) >> 16;
  return (u16)r;
}
DEVI float bf2f(u16 h) {
  union { float f; u32 u; } c; c.u = ((u32)h) << 16;
  return c.f;
}
DEVI void stage8(u16* dst, const float* src) {
  const f32x4 a = *(const f32x4*)(src);
  const f32x4 b = *(const f32x4*)(src + 4);
  union { bf16x8 v; u16 u[8]; } o;
  o.u[0] = f2bf(a[0]); o.u[1] = f2bf(a[1]); o.u[2] = f2bf(a[2]); o.u[3] = f2bf(a[3]);
  o.u[4] = f2bf(b[0]); o.u[5] = f2bf(b[1]); o.u[6] = f2bf(b[2]); o.u[7] = f2bf(b[3]);
  *(bf16x8*)dst = o.v;
}

typedef const __attribute__((address_space(1))) void* gas_ptr;
typedef __attribute__((address_space(3))) void* las_ptr;
DEVI void gload16(const void* g, void* l) {
  __builtin_amdgcn_global_load_lds((gas_ptr)g, (las_ptr)l, 16, 0, 0);
}

// ============================================================================
// fp32 -> bf16 bulk convert
// ============================================================================
__global__ __launch_bounds__(256)
void f32_to_bf16(const float* __restrict__ in, u16* __restrict__ out, int n8) {
  const int i = blockIdx.x * 256 + threadIdx.x;
  if (i >= n8) return;
  u16 tmp[8];
  stage8(tmp, in + (size_t)i * 8);
  *(bf16x8*)(out + (size_t)i * 8) = *(bf16x8*)tmp;
}

// ============================================================================
// convert_x v2: x f32 [B,N,C] -> xb bf16 (direct from regs, no LDS) and
// xbT bf16 [B,C,N] via u32 n-pair packed LDS transpose (all 32-bit LDS ops,
// <=2-way banks). Was: 16x ds_read_u16/thread -> LDS-issue-bound at 59us.
// ============================================================================
__global__ __launch_bounds__(256)
void convert_x(const float* __restrict__ x, u16* __restrict__ xb,
               u16* __restrict__ xbT) {
  __shared__ u32 LtT[64 * 33];        // [c][n-pair], pad 1 -> 8448 B
  const int ct = blockIdx.x, nt = blockIdx.y, b = blockIdx.z;
  const int t = threadIdx.x;
  const int n0 = nt * 64, c0 = ct * 64;
  const int cl = (t & 15) * 4;        // c within tile
  const int np = t >> 4;              // n-pair index 0..15
#pragma unroll
  for (int pass = 0; pass < 2; ++pass) {
    const int w = np + pass * 16;     // word index == n-pair
    const int n = w * 2;
    const float* s0 = &x[((size_t)(b * NN + n0 + n)) * CC + c0 + cl];
    const f32x4 a = *(const f32x4*)s0;
    const f32x4 bv = *(const f32x4*)(s0 + CC);
    const u16 a0 = f2bf(a[0]), a1 = f2bf(a[1]), a2 = f2bf(a[2]), a3 = f2bf(a[3]);
    const u16 b0 = f2bf(bv[0]), b1 = f2bf(bv[1]), b2 = f2bf(bv[2]), b3 = f2bf(bv[3]);
    // xb: two 8B stores straight from registers
    *(u64*)&xb[((size_t)(b * NN + n0 + n)) * CC + c0 + cl] =
        (u64)a0 | ((u64)a1 << 16) | ((u64)a2 << 32) | ((u64)a3 << 48);
    *(u64*)&xb[((size_t)(b * NN + n0 + n + 1)) * CC + c0 + cl] =
        (u64)b0 | ((u64)b1 << 16) | ((u64)b2 << 32) | ((u64)b3 << 48);
    // LDS: 4 u32 writes, each = (n, n+1) pair for one channel
    LtT[(cl + 0) * 33 + w] = (u32)a0 | ((u32)b0 << 16);
    LtT[(cl + 1) * 33 + w] = (u32)a1 | ((u32)b1 << 16);
    LtT[(cl + 2) * 33 + w] = (u32)a2 | ((u32)b2 << 16);
    LtT[(cl + 3) * 33 + w] = (u32)a3 | ((u32)b3 << 16);
  }
  __syncthreads();
#pragma unroll
  for (int pass = 0; pass < 2; ++pass) {
    const int v = pass * 256 + t;
    const int c = v >> 3, ng = v & 7;   // 8 n-values = 4 u32 words
    union { bf16x8 o; u32 q[4]; } u;
#pragma unroll
    for (int r = 0; r < 4; ++r) u.q[r] = LtT[c * 33 + ng * 4 + r];
    *(bf16x8*)&xbT[((size_t)(b * CC + c0 + c)) * NN + n0 + ng * 8] = u.o;
  }
}

// ============================================================================
// cw (f32 [m=384][c=384]) -> cwT bf16 [c][m]  (same u32-pair transpose)
// ============================================================================
__global__ __launch_bounds__(256)
void transpose_cw(const float* __restrict__ cw, u16* __restrict__ cwT) {
  __shared__ u32 LtT[64 * 33];
  const int mt = blockIdx.x, ct = blockIdx.y;
  const int t = threadIdx.x;
  const int m0 = mt * 64, c0 = ct * 64;
  const int cl = (t & 15) * 4;
  const int mp = t >> 4;
#pragma unroll
  for (int pass = 0; pass < 2; ++pass) {
    const int w = mp + pass * 16;
    const int m = w * 2;
    const float* s0 = &cw[(size_t)(m0 + m) * CC + c0 + cl];
    const f32x4 a = *(const f32x4*)s0;
    const f32x4 bv = *(const f32x4*)(s0 + CC);
#pragma unroll
    for (int i = 0; i < 4; ++i)
      LtT[(cl + i) * 33 + w] = (u32)f2bf(a[i]) | ((u32)f2bf(bv[i]) << 16);
  }
  __syncthreads();
#pragma unroll
  for (int pass = 0; pass < 2; ++pass) {
    const int v = pass * 256 + t;
    const int c = v >> 3, mg = v & 7;
    union { bf16x8 o; u32 q[4]; } u;
#pragma unroll
    for (int r = 0; r < 4; ++r) u.q[r] = LtT[c * 33 + mg * 4 + r];
    *(bf16x8*)&cwT[(size_t)(c0 + c) * CC + m0 + mg * 8] = u.o;
  }
}

// ============================================================================
// bias_fuse: bf_[o] = btop[o] + sum_m wtop[o][m]*cb[m]  (one wave per o)
// ============================================================================
__global__ __launch_bounds__(256)
void bias_fuse(const float* __restrict__ wq, const float* __restrict__ bq,
               const float* __restrict__ wkv, const float* __restrict__ bkv,
               const float* __restrict__ cb, float* __restrict__ bf_) {
  const int o = blockIdx.x * 4 + (threadIdx.x >> 6);
  const int lane = threadIdx.x & 63;
  const float* wrow;
  float b0;
  if (o < CC) { wrow = wq + (size_t)o * CC;        b0 = bq[o]; }
  else        { wrow = wkv + (size_t)(o - CC) * CC; b0 = bkv[o - CC]; }
  float s = 0.f;
  for (int m = lane; m < CC; m += 64) s += wrow[m] * cb[m];
#pragma unroll
  for (int off = 32; off; off >>= 1) s += __shfl_xor(s, off, 64);
  if (lane == 0) bf_[o] = b0 + s;
}

// ============================================================================
// colsum: sx[b][c] = sum_n xbT[b][c][n]
// ============================================================================
__global__ __launch_bounds__(256)
void colsum(const u16* __restrict__ xbT, float* __restrict__ sx) {
  const int b = blockIdx.y, c = blockIdx.x * 16 + (threadIdx.x >> 4);
  const int sl = threadIdx.x & 15;
  const u16* src = xbT + ((size_t)(b * CC + c)) * NN + sl * 256;
  float s = 0.f;
  for (int i = 0; i < 32; ++i) {
    const bf16x8 v = *(const bf16x8*)(src + i * 8);
#pragma unroll
    for (int r = 0; r < 8; ++r) s += bf2f((u16)v[r]);
  }
#pragma unroll
  for (int m = 1; m < 16; m <<= 1) s += __shfl_xor(s, m, 64);
  if (sl == 0) sx[b * CC + c] = s;
}

// ============================================================================
// proj_sx: P[b][o] = sum_c Wf[o][c] * sx[b][c], o<768
// ============================================================================
__global__ __launch_bounds__(128)
void proj_sx(const u16* __restrict__ Wf, const float* __restrict__ sx,
             float* __restrict__ P) {
  __shared__ float sl[CC];
  const int b = blockIdx.y, o = blockIdx.x * 128 + threadIdx.x;
  for (int i = threadIdx.x; i < CC; i += 128) sl[i] = sx[b * CC + i];
  __syncthreads();
  float acc = 0.f;
  const u16* wr = Wf + (size_t)o * CC;
  for (int c8 = 0; c8 < CC; c8 += 8) {
    const bf16x8 w = *(const bf16x8*)(wr + c8);
#pragma unroll
    for (int r = 0; r < 8; ++r) acc += bf2f((u16)w[r]) * sl[c8 + r];
  }
  P[b * 768 + o] = acc;
}

// ============================================================================
// Generic GEMM: C[M,N](+p partials) = A[M,K-slice] @ W[N,K-slice]^T (+bias)
// m97 structure: SINGLE 32KB staging buffer (sync-stage-sync-compute) ->
// 4 blocks/CU (was 2 with 64KB dbuf); inter-block overlap hides the barrier
// drain. T2 both-sides swizzle kept. TRI: 6 upper tiles. SWZ: XCD swizzle.
// ============================================================================
template<typename OT, int BIASMODE, int TRI = 0, int SWZ = 1>
__global__ __launch_bounds__(256)
void gemm_f(const u16* __restrict__ A, const u16* __restrict__ W,
            const float* __restrict__ bias, OT* __restrict__ C,
            int M, int N, int K, int klen, int nbn, int nbm, int tpb,
            long sA, long sW, long sC, long sCp, long sBias) {
  constexpr int BK = 64;
  __shared__ __align__(16) u16 smem[16896];   // 33792 B: 32KB staging + epilogue

  const int nx = gridDim.x;
  const int lin = blockIdx.x;
  const int lin2 = SWZ ? (lin & 7) * (nx >> 3) + (lin >> 3) : lin;
  const int b = lin2 / tpb;
  int t2 = lin2 % tpb;
  int bn, bm, p;
  if constexpr (TRI) {
    const int tl = t2 % 6; p = t2 / 6;
    bm = tl < 3 ? 0 : (tl < 5 ? 1 : 2);
    bn = tl < 3 ? tl : (tl < 5 ? tl - 2 : 2);
  } else {
    bn = t2 % nbn; t2 /= nbn;
    bm = t2 % nbm;
    p = t2 / nbm;
  }
  A += (size_t)b * sA; W += (size_t)b * sW;
  C += (size_t)b * sC + (size_t)p * sCp;
  if (BIASMODE) bias += (size_t)b * sBias;

  const int t = threadIdx.x;
  const int wid = t >> 6, lane = t & 63;
  const int wr = wid >> 1, wc = wid & 1;
  const int row0 = bm * 128, col0 = bn * 128;
  const int lrow = lane & 15;
  const int lswz = (lane & 7) << 3;
  const int kstart = p * klen;

  const int arow = t >> 3;
  const int scol = ((t & 7) ^ ((t >> 3) & 7)) * 8;   // inverse-swizzled source
  const u16* Ag = A + (size_t)(row0 + arow) * K + scol;
  const u16* Wg = W + (size_t)(col0 + arow) * K + scol;
  u16* As = smem;
  u16* Bs = smem + 8192;

  f32x4 acc[4][4] = {};
  const int NT = klen >> 6;

  for (int kt = 0; kt < NT; ++kt) {
    __syncthreads();                 // previous tile's LDS reads done
    const int k0 = kstart + kt * BK;
    u16* Al = As + t * 8;
    u16* Bl = Bs + t * 8;
#pragma unroll
    for (int it = 0; it < 4; ++it) {
      gload16(Ag + (size_t)(it * 32) * K + k0, Al + it * 2048);
      gload16(Wg + (size_t)(it * 32) * K + k0, Bl + it * 2048);
    }
    __syncthreads();                 // vmcnt(0) drain: tile visible
#pragma unroll
    for (int kk = 0; kk < 2; ++kk) {
      const int lk = (kk * 32 + (lane >> 4) * 8) ^ lswz;
      bf16x8 af[4], bf[4];
#pragma unroll
      for (int i = 0; i < 4; ++i)
        af[i] = *(const bf16x8*)&As[(wr * 64 + i * 16 + lrow) * BK + lk];
#pragma unroll
      for (int j = 0; j < 4; ++j)
        bf[j] = *(const bf16x8*)&Bs[(wc * 64 + j * 16 + lrow) * BK + lk];
#pragma unroll
      for (int i = 0; i < 4; ++i)
#pragma unroll
        for (int j = 0; j < 4; ++j)
          acc[i][j] = __builtin_amdgcn_mfma_f32_16x16x32_bf16(af[i], bf[j], acc[i][j], 0, 0, 0);
    }
  }

  const int lr = (lane >> 4) * 4;
  if constexpr (sizeof(OT) == 2) {
    __syncthreads();                 // all waves done with staging LDS
    u16* Ct = smem;                  // [128][132]
#pragma unroll
    for (int i = 0; i < 4; ++i)
#pragma unroll
      for (int j = 0; j < 4; ++j) {
        const int ccol = wc * 64 + j * 16 + lrow;
        float bv = 0.f;
        if constexpr (BIASMODE == 1) bv = bias[col0 + ccol];
#pragma unroll
        for (int r = 0; r < 4; ++r) {
          const int rrow = wr * 64 + i * 16 + lr + r;
          float b2 = bv;
          if constexpr (BIASMODE == 2) b2 = bias[row0 + rrow];
          Ct[rrow * 132 + ccol] = f2bf(acc[i][j][r] + b2);
        }
      }
    __syncthreads();
#pragma unroll
    for (int it = 0; it < 8; ++it) {
      const int id = it * 256 + t;
      const int row = id >> 4, c16 = (id & 15) * 8;
      *(bf16x8*)((u16*)C + (size_t)(row0 + row) * N + col0 + c16) =
          *(const bf16x8*)&Ct[row * 132 + c16];
    }
  } else {
    const int orow = row0 + wr * 64, ocol = col0 + wc * 64;
#pragma unroll
    for (int i = 0; i < 4; ++i)
#pragma unroll
      for (int j = 0; j < 4; ++j) {
        const int cc2 = ocol + j * 16 + lrow;
        float bv = 0.f;
        if constexpr (BIASMODE == 1) bv = bias[cc2];
#pragma unroll
        for (int r = 0; r < 4; ++r) {
          const int rr = orow + i * 16 + lr + r;
          float b2 = bv;
          if constexpr (BIASMODE == 2) b2 = bias[rr];
          C[(size_t)rr * N + cc2] = acc[i][j][r] + b2;
        }
      }
  }
}

// ============================================================================
// reduceG: Gbf[b][i][j] = bf16( sum_p Gpart[b][p][upper(i,j)] )  (symmetric)
// ============================================================================
__global__ __launch_bounds__(256)
void reduceG(const float* __restrict__ Gp, u16* __restrict__ Gbf) {
  const int b = blockIdx.y;
  const int e = blockIdx.x * 256 + threadIdx.x;
  const int i = e / CC, j = e % CC;
  const int ee = (i <= j) ? e : (j * CC + i);
  const float* s = Gp + (size_t)b * 4 * 147456 + ee;
  Gbf[(size_t)b * 147456 + e] =
      f2bf(s[0] + s[147456] + s[2 * 147456] + s[3 * 147456]);
}

// ============================================================================
// s_softmax: per (b,h): S = M1_h @ Uk_h^T + rank-1 terms, *N^-0.5, softmax;
// AU = attn @ Uv_h -> AUb rows (i*8+h); rbias = attn @ bv'
// ============================================================================
__global__ __launch_bounds__(256)
void s_softmax(const u16* __restrict__ M1g, const u16* __restrict__ Wf,
               const float* __restrict__ bf_, const float* __restrict__ P,
               const u16* __restrict__ UvT, u16* __restrict__ AUb,
               float* __restrict__ rbias) {
  __shared__ float Sf[48 * 52];
  __shared__ __align__(16) u16 att[48 * 56];
  const int bh = blockIdx.x, b = bh >> 3, h = bh & 7;
  const int t = threadIdx.x, wid = t >> 6, lane = t & 63;
  const int lrow = lane & 15, lkq = lane >> 4;

  if (wid < 3) {
    f32x4 acc[3] = {};
    const u16* Arow = M1g + (size_t)b * 147456 + (size_t)(h * 48 + wid * 16 + lrow) * CC;
    const u16* Brow = Wf + (size_t)(CC + h * 48) * CC;    // Uk
    for (int ks = 0; ks < 12; ++ks) {
      const int k = ks * 32 + lkq * 8;
      const bf16x8 af = *(const bf16x8*)(Arow + k);
#pragma unroll
      for (int j = 0; j < 3; ++j) {
        const bf16x8 bfr = *(const bf16x8*)(Brow + (size_t)(j * 16 + lrow) * CC + k);
        acc[j] = __builtin_amdgcn_mfma_f32_16x16x32_bf16(af, bfr, acc[j], 0, 0, 0);
      }
    }
    const int lr = lkq * 4;
#pragma unroll
    for (int j = 0; j < 3; ++j)
#pragma unroll
      for (int r = 0; r < 4; ++r)
        Sf[(wid * 16 + lr + r) * 52 + j * 16 + lrow] = acc[j][r];
  }
  __syncthreads();

  if (t < 48) {
    const float bi = bf_[h * 48 + t];
    const float pq = P[b * 768 + h * 48 + t];
    float row[48];
    float mx = -1e30f;
#pragma unroll
    for (int j = 0; j < 48; ++j) {
      const float g = bf_[CC + h * 48 + j];
      const float pk = P[b * 768 + CC + h * 48 + j];
      const float s = (Sf[t * 52 + j] + bi * pk + pq * g + 4096.f * bi * g) * 0.015625f;
      row[j] = s;
      mx = fmaxf(mx, s);
    }
    float sum = 0.f;
#pragma unroll
    for (int j = 0; j < 48; ++j) { row[j] = __expf(row[j] - mx); sum += row[j]; }
    const float inv = 1.f / sum;
    float rb = 0.f;
#pragma unroll
    for (int j = 0; j < 48; ++j) {
      const float a = row[j] * inv;
      att[t * 56 + j] = f2bf(a);
      rb += a * bf_[2 * CC + h * 48 + j];
    }
#pragma unroll
    for (int j = 48; j < 56; ++j) att[t * 56 + j] = 0;
    rbias[b * CC + t * 8 + h] = rb;
  }
  __syncthreads();

  f32x4 acc[3][6] = {};
  const u16* Vbase = UvT + h * 48;
  const bf16x8 z = {};
#pragma unroll
  for (int kk = 0; kk < 2; ++kk) {
    const int k = kk * 32 + lkq * 8;
    bf16x8 af[3];
#pragma unroll
    for (int i = 0; i < 3; ++i) {
      af[i] = *(const bf16x8*)&att[(i * 16 + lrow) * 56 + k];
      if (k >= 48) af[i] = z;
    }
#pragma unroll
    for (int ct = 0; ct < 6; ++ct) {
      const int c = wid * 96 + ct * 16 + lrow;
      bf16x8 bfr = *(const bf16x8*)(Vbase + (size_t)c * CC + k);
      if (k >= 48) bfr = z;
#pragma unroll
      for (int i = 0; i < 3; ++i)
        acc[i][ct] = __builtin_amdgcn_mfma_f32_16x16x32_bf16(af[i], bfr, acc[i][ct], 0, 0, 0);
    }
  }
  const int lr = lkq * 4;
#pragma unroll
  for (int i = 0; i < 3; ++i)
#pragma unroll
    for (int ct = 0; ct < 6; ++ct) {
      const int c = wid * 96 + ct * 16 + lrow;
#pragma unroll
      for (int r = 0; r < 4; ++r) {
        const int ii = i * 16 + lr + r;
        AUb[(size_t)b * 147456 + (size_t)(ii * 8 + h) * CC + c] = f2bf(acc[i][ct][r]);
      }
    }
}

// ============================================================================
extern "C" void kernel_launch(void* const* d_in, const int* in_sizes, int n_in,
                              void* d_out, int out_size, void* d_ws, size_t ws_size,
                              hipStream_t stream) {
  const float* x      = (const float*)d_in[0];
  const float* conv_w = (const float*)d_in[1];
  const float* conv_b = (const float*)d_in[2];
  const float* wq     = (const float*)d_in[3];
  const float* bq     = (const float*)d_in[4];
  const float* wkv    = (const float*)d_in[5];
  const float* bkv    = (const float*)d_in[6];
  const float* wp     = (const float*)d_in[7];
  const float* bp     = (const float*)d_in[8];
  float* y = (float*)d_out;

  char* ws = (char*)d_ws;
  u16*   Wf    = (u16*)(ws + 0);              //   884,736 (rows 768+ unused)
  float* bf_   = (float*)(ws + 884736);       //     4,608
  u16*   wpb   = (u16*)(ws + 889344);         //   294,912
  u16*   UvT   = (u16*)(ws + 1184256);        //   294,912
  float* sx    = (float*)(ws + 1479168);      //    24,576
  float* P     = (float*)(ws + 1503744);      //    49,152
  float* rb    = (float*)(ws + 1552896);      //    24,576
  u16*   M1g   = (u16*)(ws + 1577472);        // 4,718,592
  u16*   Gbf   = (u16*)(ws + 6296064);        // 4,718,592
  u16*   AUb   = (u16*)(ws + 11014656);       // 4,718,592
  float* Gpart = (float*)(ws + 15733248);     // 37,748,736
  u16*   wtopb = (u16*)(ws + 53481984);       //   884,736  [wq;wkv] bf16
  u16*   cwTb  = (u16*)(ws + 54366720);       //   294,912  cw^T bf16
  u16*   xb    = (u16*)(ws + 54661632);       // 50,331,648
  u16*   xbT   = (u16*)(ws + 104993280);      // 50,331,648 (dead after gram)
  u16*   R     = xbT;                         // aliases xbT
  // total ws use: 155,324,928 B

  convert_x<<<dim3(6, 64, 16), dim3(256), 0, stream>>>(x, xb, xbT);
  f32_to_bf16<<<dim3(72), dim3(256), 0, stream>>>(wp, wpb, (CC * CC) / 8);
  f32_to_bf16<<<dim3(72), dim3(256), 0, stream>>>(wq, wtopb, (CC * CC) / 8);
  f32_to_bf16<<<dim3(144), dim3(256), 0, stream>>>(wkv, wtopb + CC * CC,
                                                   (2 * CC * CC) / 8);
  transpose_cw<<<dim3(6, 6), dim3(256), 0, stream>>>(conv_w, cwTb);
  bias_fuse<<<dim3(288), dim3(256), 0, stream>>>(wq, bq, wkv, bkv, conv_b, bf_);
  // Wf[0:768] = wtop @ cw : C[o][c] = sum_m wtopb[o][m]*cwTb[c][m]
  gemm_f<u16, 0, 0, 0><<<dim3(18), dim3(256), 0, stream>>>(
      wtopb, cwTb, nullptr, Wf, 2 * CC, CC, CC, CC, 3, 6, 18,
      0, 0, 0, 0, 0);
  // UvT[c][j] = sum_m cwTb[c][m]*wkv_v[j][m]  (wkv_v = wtopb rows 768+)
  gemm_f<u16, 0, 0, 0><<<dim3(9), dim3(256), 0, stream>>>(
      cwTb, wtopb + 2 * CC * CC, nullptr, UvT, CC, CC, CC, CC, 3, 3, 9,
      0, 0, 0, 0, 0);
  colsum<<<dim3(24, 16), dim3(256), 0, stream>>>(xbT, sx);
  proj_sx<<<dim3(6, 16), dim3(128), 0, stream>>>(Wf, sx, P);
  // Gram partials (symmetric: 6 upper tiles only), split-K 4
  gemm_f<float, 0, 1><<<dim3(384), dim3(256), 0, stream>>>(
      xbT, xbT, nullptr, Gpart, CC, CC, NN, 1024, 3, 3, 24,
      (long)CC * NN, (long)CC * NN, 4L * 147456, 147456, 0);
  reduceG<<<dim3(576, 16), dim3(256), 0, stream>>>(Gpart, Gbf);
  // M1g[b] = Uq @ Gx_b
  gemm_f<u16, 0><<<dim3(144), dim3(256), 0, stream>>>(
      Wf, Gbf, nullptr, M1g, CC, CC, CC, CC, 3, 3, 9,
      0, 147456, 147456, 0, 0);
  s_softmax<<<dim3(128), dim3(256), 0, stream>>>(M1g, Wf, bf_, P, UvT, AUb, rb);
  // R[b] = AUb[b] @ xb_b^T + rbias (row-bias)
  gemm_f<u16, 2><<<dim3(1536), dim3(256), 0, stream>>>(
      AUb, xb, rb, R, CC, NN, CC, CC, 32, 3, 96,
      147456, (long)NN * CC, (long)NN * CC, 0, CC);
  // y = R @ wpb^T + bp
  gemm_f<float, 1><<<dim3(1536), dim3(256), 0, stream>>>(
      R, wpb, bp, y, BB * NN, CC, CC, CC, 3, 512, 1536,
      0, 0, 0, 0, 0);
}

// Round 8
// 229.079 us; speedup vs baseline: 1.0496x; 1.0496x over previous
//
#include <hip/hip_runtime.h>
#include <hip/hip_bf16.h>
#include <stdint.h>

#define DEVI static __device__ __forceinline__

typedef __attribute__((ext_vector_type(4))) float f32x4;
typedef __attribute__((ext_vector_type(8))) short bf16x8;
typedef unsigned short u16;
typedef unsigned int u32;
typedef unsigned long long u64;

// B=16, N=4096, C=384, H=8, D=48
#define BB 16
#define NN 4096
#define CC 384
#define HH 8
#define DD 48

DEVI u16 f2bf(float f) {
  union { float f; u32 u; } c; c.f = f;
  u32 u = c.u;
  u32 r = (u + 0x7FFFu + ((u >> 16) & 1u)) >> 16;
  return (u16)r;
}
DEVI float bf2f(u16 h) {
  union { float f; u32 u; } c; c.u = ((u32)h) << 16;
  return c.f;
}
DEVI void stage8(u16* dst, const float* src) {
  const f32x4 a = *(const f32x4*)(src);
  const f32x4 b = *(const f32x4*)(src + 4);
  union { bf16x8 v; u16 u[8]; } o;
  o.u[0] = f2bf(a[0]); o.u[1] = f2bf(a[1]); o.u[2] = f2bf(a[2]); o.u[3] = f2bf(a[3]);
  o.u[4] = f2bf(b[0]); o.u[5] = f2bf(b[1]); o.u[6] = f2bf(b[2]); o.u[7] = f2bf(b[3]);
  *(bf16x8*)dst = o.v;
}

typedef const __attribute__((address_space(1))) void* gas_ptr;
typedef __attribute__((address_space(3))) void* las_ptr;
DEVI void gload16(const void* g, void* l) {
  __builtin_amdgcn_global_load_lds((gas_ptr)g, (las_ptr)l, 16, 0, 0);
}

// ============================================================================
// fp32 -> bf16 bulk convert
// ============================================================================
__global__ __launch_bounds__(256)
void f32_to_bf16(const float* __restrict__ in, u16* __restrict__ out, int n8) {
  const int i = blockIdx.x * 256 + threadIdx.x;
  if (i >= n8) return;
  u16 tmp[8];
  stage8(tmp, in + (size_t)i * 8);
  *(bf16x8*)(out + (size_t)i * 8) = *(bf16x8*)tmp;
}

// ============================================================================
// convert_x v2: x f32 [B,N,C] -> xb bf16 (direct from regs) and xbT bf16
// [B,C,N] via u32 n-pair packed LDS transpose (all 32-bit LDS ops, <=2-way).
// ============================================================================
__global__ __launch_bounds__(256)
void convert_x(const float* __restrict__ x, u16* __restrict__ xb,
               u16* __restrict__ xbT) {
  __shared__ u32 LtT[64 * 33];        // [c][n-pair], pad 1 -> 8448 B
  const int ct = blockIdx.x, nt = blockIdx.y, b = blockIdx.z;
  const int t = threadIdx.x;
  const int n0 = nt * 64, c0 = ct * 64;
  const int cl = (t & 15) * 4;
  const int np = t >> 4;
#pragma unroll
  for (int pass = 0; pass < 2; ++pass) {
    const int w = np + pass * 16;
    const int n = w * 2;
    const float* s0 = &x[((size_t)(b * NN + n0 + n)) * CC + c0 + cl];
    const f32x4 a = *(const f32x4*)s0;
    const f32x4 bv = *(const f32x4*)(s0 + CC);
    const u16 a0 = f2bf(a[0]), a1 = f2bf(a[1]), a2 = f2bf(a[2]), a3 = f2bf(a[3]);
    const u16 b0 = f2bf(bv[0]), b1 = f2bf(bv[1]), b2 = f2bf(bv[2]), b3 = f2bf(bv[3]);
    *(u64*)&xb[((size_t)(b * NN + n0 + n)) * CC + c0 + cl] =
        (u64)a0 | ((u64)a1 << 16) | ((u64)a2 << 32) | ((u64)a3 << 48);
    *(u64*)&xb[((size_t)(b * NN + n0 + n + 1)) * CC + c0 + cl] =
        (u64)b0 | ((u64)b1 << 16) | ((u64)b2 << 32) | ((u64)b3 << 48);
    LtT[(cl + 0) * 33 + w] = (u32)a0 | ((u32)b0 << 16);
    LtT[(cl + 1) * 33 + w] = (u32)a1 | ((u32)b1 << 16);
    LtT[(cl + 2) * 33 + w] = (u32)a2 | ((u32)b2 << 16);
    LtT[(cl + 3) * 33 + w] = (u32)a3 | ((u32)b3 << 16);
  }
  __syncthreads();
#pragma unroll
  for (int pass = 0; pass < 2; ++pass) {
    const int v = pass * 256 + t;
    const int c = v >> 3, ng = v & 7;
    union { bf16x8 o; u32 q[4]; } u;
#pragma unroll
    for (int r = 0; r < 4; ++r) u.q[r] = LtT[c * 33 + ng * 4 + r];
    *(bf16x8*)&xbT[((size_t)(b * CC + c0 + c)) * NN + n0 + ng * 8] = u.o;
  }
}

// ============================================================================
// cw (f32 [m=384][c=384]) -> cwT bf16 [c][m]
// ============================================================================
__global__ __launch_bounds__(256)
void transpose_cw(const float* __restrict__ cw, u16* __restrict__ cwT) {
  __shared__ u32 LtT[64 * 33];
  const int mt = blockIdx.x, ct = blockIdx.y;
  const int t = threadIdx.x;
  const int m0 = mt * 64, c0 = ct * 64;
  const int cl = (t & 15) * 4;
  const int mp = t >> 4;
#pragma unroll
  for (int pass = 0; pass < 2; ++pass) {
    const int w = mp + pass * 16;
    const int m = w * 2;
    const float* s0 = &cw[(size_t)(m0 + m) * CC + c0 + cl];
    const f32x4 a = *(const f32x4*)s0;
    const f32x4 bv = *(const f32x4*)(s0 + CC);
#pragma unroll
    for (int i = 0; i < 4; ++i)
      LtT[(cl + i) * 33 + w] = (u32)f2bf(a[i]) | ((u32)f2bf(bv[i]) << 16);
  }
  __syncthreads();
#pragma unroll
  for (int pass = 0; pass < 2; ++pass) {
    const int v = pass * 256 + t;
    const int c = v >> 3, mg = v & 7;
    union { bf16x8 o; u32 q[4]; } u;
#pragma unroll
    for (int r = 0; r < 4; ++r) u.q[r] = LtT[c * 33 + mg * 4 + r];
    *(bf16x8*)&cwT[(size_t)(c0 + c) * CC + m0 + mg * 8] = u.o;
  }
}

// ============================================================================
// bias_fuse: bf_[o] = btop[o] + sum_m wtop[o][m]*cb[m]  (one wave per o)
// ============================================================================
__global__ __launch_bounds__(256)
void bias_fuse(const float* __restrict__ wq, const float* __restrict__ bq,
               const float* __restrict__ wkv, const float* __restrict__ bkv,
               const float* __restrict__ cb, float* __restrict__ bf_) {
  const int o = blockIdx.x * 4 + (threadIdx.x >> 6);
  const int lane = threadIdx.x & 63;
  const float* wrow;
  float b0;
  if (o < CC) { wrow = wq + (size_t)o * CC;        b0 = bq[o]; }
  else        { wrow = wkv + (size_t)(o - CC) * CC; b0 = bkv[o - CC]; }
  float s = 0.f;
  for (int m = lane; m < CC; m += 64) s += wrow[m] * cb[m];
#pragma unroll
  for (int off = 32; off; off >>= 1) s += __shfl_xor(s, off, 64);
  if (lane == 0) bf_[o] = b0 + s;
}

// ============================================================================
// colsum: sx[b][c] = sum_n xbT[b][c][n]
// ============================================================================
__global__ __launch_bounds__(256)
void colsum(const u16* __restrict__ xbT, float* __restrict__ sx) {
  const int b = blockIdx.y, c = blockIdx.x * 16 + (threadIdx.x >> 4);
  const int sl = threadIdx.x & 15;
  const u16* src = xbT + ((size_t)(b * CC + c)) * NN + sl * 256;
  float s = 0.f;
  for (int i = 0; i < 32; ++i) {
    const bf16x8 v = *(const bf16x8*)(src + i * 8);
#pragma unroll
    for (int r = 0; r < 8; ++r) s += bf2f((u16)v[r]);
  }
#pragma unroll
  for (int m = 1; m < 16; m <<= 1) s += __shfl_xor(s, m, 64);
  if (sl == 0) sx[b * CC + c] = s;
}

// ============================================================================
// proj_sx: P[b][o] = sum_c Wf[o][c] * sx[b][c], o<768
// ============================================================================
__global__ __launch_bounds__(128)
void proj_sx(const u16* __restrict__ Wf, const float* __restrict__ sx,
             float* __restrict__ P) {
  __shared__ float sl[CC];
  const int b = blockIdx.y, o = blockIdx.x * 128 + threadIdx.x;
  for (int i = threadIdx.x; i < CC; i += 128) sl[i] = sx[b * CC + i];
  __syncthreads();
  float acc = 0.f;
  const u16* wr = Wf + (size_t)o * CC;
  for (int c8 = 0; c8 < CC; c8 += 8) {
    const bf16x8 w = *(const bf16x8*)(wr + c8);
#pragma unroll
    for (int r = 0; r < 8; ++r) acc += bf2f((u16)w[r]) * sl[c8 + r];
  }
  P[b * 768 + o] = acc;
}

// ============================================================================
// Generic GEMM: C[M,N](+p partials) = A[M,K-slice] @ W[N,K-slice]^T (+bias)
// R6 dbuf structure (issue-early / wait-late = minimum 2-phase pipeline):
// stage(next) BEFORE ds_read+MFMA(cur), one vmcnt(0)+barrier per tile.
// T2 both-sides swizzle. fp32 epilogue: LDS-restage halves -> dwordx4 stores.
// TRI: 6 upper tiles. SWZ: XCD swizzle (grid%8==0 only).
// ============================================================================
template<typename OT, int BIASMODE, int TRI = 0, int SWZ = 1>
__global__ __launch_bounds__(256)
void gemm_f(const u16* __restrict__ A, const u16* __restrict__ W,
            const float* __restrict__ bias, OT* __restrict__ C,
            int M, int N, int K, int klen, int nbn, int nbm, int tpb,
            long sA, long sW, long sC, long sCp, long sBias) {
  constexpr int BK = 64;
  __shared__ __align__(16) u16 smem[32768];   // 64 KB: 2 x (As 8192 | Bs 8192)

  const int nx = gridDim.x;
  const int lin = blockIdx.x;
  const int lin2 = SWZ ? (lin & 7) * (nx >> 3) + (lin >> 3) : lin;
  const int b = lin2 / tpb;
  int t2 = lin2 % tpb;
  int bn, bm, p;
  if constexpr (TRI) {
    const int tl = t2 % 6; p = t2 / 6;
    bm = tl < 3 ? 0 : (tl < 5 ? 1 : 2);
    bn = tl < 3 ? tl : (tl < 5 ? tl - 2 : 2);
  } else {
    bn = t2 % nbn; t2 /= nbn;
    bm = t2 % nbm;
    p = t2 / nbm;
  }
  A += (size_t)b * sA; W += (size_t)b * sW;
  C += (size_t)b * sC + (size_t)p * sCp;
  if (BIASMODE) bias += (size_t)b * sBias;

  const int t = threadIdx.x;
  const int wid = t >> 6, lane = t & 63;
  const int wr = wid >> 1, wc = wid & 1;
  const int row0 = bm * 128, col0 = bn * 128;
  const int lrow = lane & 15;
  const int lswz = (lane & 7) << 3;
  const int kstart = p * klen;

  const int arow = t >> 3;
  const int scol = ((t & 7) ^ ((t >> 3) & 7)) * 8;   // inverse-swizzled source
  const u16* Ag = A + (size_t)(row0 + arow) * K + scol;
  const u16* Wg = W + (size_t)(col0 + arow) * K + scol;

  f32x4 acc[4][4] = {};
  const int NT = klen >> 6;

  auto stage = [&](int buf, int kt) {
    u16* Al = smem + buf * 16384 + t * 8;
    u16* Bl = smem + buf * 16384 + 8192 + t * 8;
    const int k0 = kstart + kt * BK;
#pragma unroll
    for (int it = 0; it < 4; ++it) {
      gload16(Ag + (size_t)(it * 32) * K + k0, Al + it * 2048);
      gload16(Wg + (size_t)(it * 32) * K + k0, Bl + it * 2048);
    }
  };

  stage(0, 0);
  __syncthreads();                 // drain tile 0
  int cur = 0;
  for (int kt = 0; kt < NT; ++kt) {
    if (kt + 1 < NT) stage(cur ^ 1, kt + 1);     // issue-early (overlaps MFMA)
    const u16* As = smem + cur * 16384;
    const u16* Bs = smem + cur * 16384 + 8192;
#pragma unroll
    for (int kk = 0; kk < 2; ++kk) {
      const int lk = (kk * 32 + (lane >> 4) * 8) ^ lswz;
      bf16x8 af[4], bf[4];
#pragma unroll
      for (int i = 0; i < 4; ++i)
        af[i] = *(const bf16x8*)&As[(wr * 64 + i * 16 + lrow) * BK + lk];
#pragma unroll
      for (int j = 0; j < 4; ++j)
        bf[j] = *(const bf16x8*)&Bs[(wc * 64 + j * 16 + lrow) * BK + lk];
#pragma unroll
      for (int i = 0; i < 4; ++i)
#pragma unroll
        for (int j = 0; j < 4; ++j)
          acc[i][j] = __builtin_amdgcn_mfma_f32_16x16x32_bf16(af[i], bf[j], acc[i][j], 0, 0, 0);
    }
    __syncthreads();               // wait-late: drains next tile's loads + LDS reads
    cur ^= 1;
  }

  const int lr = (lane >> 4) * 4;
  if constexpr (sizeof(OT) == 2) {
    u16* Ct = smem;                 // [128][132] bf16 = 33792 B
#pragma unroll
    for (int i = 0; i < 4; ++i)
#pragma unroll
      for (int j = 0; j < 4; ++j) {
        const int ccol = wc * 64 + j * 16 + lrow;
        float bv = 0.f;
        if constexpr (BIASMODE == 1) bv = bias[col0 + ccol];
#pragma unroll
        for (int r = 0; r < 4; ++r) {
          const int rrow = wr * 64 + i * 16 + lr + r;
          float b2 = bv;
          if constexpr (BIASMODE == 2) b2 = bias[row0 + rrow];
          Ct[rrow * 132 + ccol] = f2bf(acc[i][j][r] + b2);
        }
      }
    __syncthreads();
#pragma unroll
    for (int it = 0; it < 8; ++it) {
      const int id = it * 256 + t;
      const int row = id >> 4, c16 = (id & 15) * 8;
      *(bf16x8*)((u16*)C + (size_t)(row0 + row) * N + col0 + c16) =
          *(const bf16x8*)&Ct[row * 132 + c16];
    }
  } else {
    // fp32: restage per 64-row half through LDS -> 16B vector stores
    float* Ct = (float*)smem;       // [64][132] f32 = 33792 B
#pragma unroll
    for (int p2 = 0; p2 < 2; ++p2) {
      if (wr == p2) {
#pragma unroll
        for (int i = 0; i < 4; ++i)
#pragma unroll
          for (int j = 0; j < 4; ++j) {
            const int ccol = wc * 64 + j * 16 + lrow;
            float bv = 0.f;
            if constexpr (BIASMODE == 1) bv = bias[col0 + ccol];
#pragma unroll
            for (int r = 0; r < 4; ++r) {
              const int rrow = i * 16 + lr + r;     // row within half
              float b2 = bv;
              if constexpr (BIASMODE == 2) b2 = bias[row0 + p2 * 64 + rrow];
              Ct[rrow * 132 + ccol] = acc[i][j][r] + b2;
            }
          }
      }
      __syncthreads();
#pragma unroll
      for (int it = 0; it < 8; ++it) {
        const int id = it * 256 + t;               // 2048 chunks of 4 f32
        const int row = id >> 5, c4 = (id & 31) * 4;
        *(f32x4*)((float*)C + (size_t)(row0 + p2 * 64 + row) * N + col0 + c4) =
            *(const f32x4*)&Ct[row * 132 + c4];
      }
      __syncthreads();
    }
  }
}

// ============================================================================
// reduceG: Gbf[b][i][j] = bf16( sum_p Gpart[b][p][upper(i,j)] )  (symmetric)
// ============================================================================
__global__ __launch_bounds__(256)
void reduceG(const float* __restrict__ Gp, u16* __restrict__ Gbf) {
  const int b = blockIdx.y;
  const int e = blockIdx.x * 256 + threadIdx.x;
  const int i = e / CC, j = e % CC;
  const int ee = (i <= j) ? e : (j * CC + i);
  const float* s = Gp + (size_t)b * 4 * 147456 + ee;
  Gbf[(size_t)b * 147456 + e] =
      f2bf(s[0] + s[147456] + s[2 * 147456] + s[3 * 147456]);
}

// ============================================================================
// s_softmax: per (b,h): S = M1_h @ Uk_h^T + rank-1 terms, *N^-0.5, softmax;
// AU = attn @ Uv_h -> AUb rows (i*8+h); rbias = attn @ bv'
// ============================================================================
__global__ __launch_bounds__(256)
void s_softmax(const u16* __restrict__ M1g, const u16* __restrict__ Wf,
               const float* __restrict__ bf_, const float* __restrict__ P,
               const u16* __restrict__ UvT, u16* __restrict__ AUb,
               float* __restrict__ rbias) {
  __shared__ float Sf[48 * 52];
  __shared__ __align__(16) u16 att[48 * 56];
  const int bh = blockIdx.x, b = bh >> 3, h = bh & 7;
  const int t = threadIdx.x, wid = t >> 6, lane = t & 63;
  const int lrow = lane & 15, lkq = lane >> 4;

  if (wid < 3) {
    f32x4 acc[3] = {};
    const u16* Arow = M1g + (size_t)b * 147456 + (size_t)(h * 48 + wid * 16 + lrow) * CC;
    const u16* Brow = Wf + (size_t)(CC + h * 48) * CC;    // Uk
    for (int ks = 0; ks < 12; ++ks) {
      const int k = ks * 32 + lkq * 8;
      const bf16x8 af = *(const bf16x8*)(Arow + k);
#pragma unroll
      for (int j = 0; j < 3; ++j) {
        const bf16x8 bfr = *(const bf16x8*)(Brow + (size_t)(j * 16 + lrow) * CC + k);
        acc[j] = __builtin_amdgcn_mfma_f32_16x16x32_bf16(af, bfr, acc[j], 0, 0, 0);
      }
    }
    const int lr = lkq * 4;
#pragma unroll
    for (int j = 0; j < 3; ++j)
#pragma unroll
      for (int r = 0; r < 4; ++r)
        Sf[(wid * 16 + lr + r) * 52 + j * 16 + lrow] = acc[j][r];
  }
  __syncthreads();

  if (t < 48) {
    const float bi = bf_[h * 48 + t];
    const float pq = P[b * 768 + h * 48 + t];
    float row[48];
    float mx = -1e30f;
#pragma unroll
    for (int j = 0; j < 48; ++j) {
      const float g = bf_[CC + h * 48 + j];
      const float pk = P[b * 768 + CC + h * 48 + j];
      const float s = (Sf[t * 52 + j] + bi * pk + pq * g + 4096.f * bi * g) * 0.015625f;
      row[j] = s;
      mx = fmaxf(mx, s);
    }
    float sum = 0.f;
#pragma unroll
    for (int j = 0; j < 48; ++j) { row[j] = __expf(row[j] - mx); sum += row[j]; }
    const float inv = 1.f / sum;
    float rb = 0.f;
#pragma unroll
    for (int j = 0; j < 48; ++j) {
      const float a = row[j] * inv;
      att[t * 56 + j] = f2bf(a);
      rb += a * bf_[2 * CC + h * 48 + j];
    }
#pragma unroll
    for (int j = 48; j < 56; ++j) att[t * 56 + j] = 0;
    rbias[b * CC + t * 8 + h] = rb;
  }
  __syncthreads();

  f32x4 acc[3][6] = {};
  const u16* Vbase = UvT + h * 48;
  const bf16x8 z = {};
#pragma unroll
  for (int kk = 0; kk < 2; ++kk) {
    const int k = kk * 32 + lkq * 8;
    bf16x8 af[3];
#pragma unroll
    for (int i = 0; i < 3; ++i) {
      af[i] = *(const bf16x8*)&att[(i * 16 + lrow) * 56 + k];
      if (k >= 48) af[i] = z;
    }
#pragma unroll
    for (int ct = 0; ct < 6; ++ct) {
      const int c = wid * 96 + ct * 16 + lrow;
      bf16x8 bfr = *(const bf16x8*)(Vbase + (size_t)c * CC + k);
      if (k >= 48) bfr = z;
#pragma unroll
      for (int i = 0; i < 3; ++i)
        acc[i][ct] = __builtin_amdgcn_mfma_f32_16x16x32_bf16(af[i], bfr, acc[i][ct], 0, 0, 0);
    }
  }
  const int lr = lkq * 4;
#pragma unroll
  for (int i = 0; i < 3; ++i)
#pragma unroll
    for (int ct = 0; ct < 6; ++ct) {
      const int c = wid * 96 + ct * 16 + lrow;
#pragma unroll
      for (int r = 0; r < 4; ++r) {
        const int ii = i * 16 + lr + r;
        AUb[(size_t)b * 147456 + (size_t)(ii * 8 + h) * CC + c] = f2bf(acc[i][ct][r]);
      }
    }
}

// ============================================================================
extern "C" void kernel_launch(void* const* d_in, const int* in_sizes, int n_in,
                              void* d_out, int out_size, void* d_ws, size_t ws_size,
                              hipStream_t stream) {
  const float* x      = (const float*)d_in[0];
  const float* conv_w = (const float*)d_in[1];
  const float* conv_b = (const float*)d_in[2];
  const float* wq     = (const float*)d_in[3];
  const float* bq     = (const float*)d_in[4];
  const float* wkv    = (const float*)d_in[5];
  const float* bkv    = (const float*)d_in[6];
  const float* wp     = (const float*)d_in[7];
  const float* bp     = (const float*)d_in[8];
  float* y = (float*)d_out;

  char* ws = (char*)d_ws;
  u16*   Wf    = (u16*)(ws + 0);              //   884,736 (rows 768+ unused)
  float* bf_   = (float*)(ws + 884736);       //     4,608
  u16*   wpb   = (u16*)(ws + 889344);         //   294,912
  u16*   UvT   = (u16*)(ws + 1184256);        //   294,912
  float* sx    = (float*)(ws + 1479168);      //    24,576
  float* P     = (float*)(ws + 1503744);      //    49,152
  float* rb    = (float*)(ws + 1552896);      //    24,576
  u16*   M1g   = (u16*)(ws + 1577472);        // 4,718,592
  u16*   Gbf   = (u16*)(ws + 6296064);        // 4,718,592
  u16*   AUb   = (u16*)(ws + 11014656);       // 4,718,592
  float* Gpart = (float*)(ws + 15733248);     // 37,748,736
  u16*   wtopb = (u16*)(ws + 53481984);       //   884,736  [wq;wkv] bf16
  u16*   cwTb  = (u16*)(ws + 54366720);       //   294,912  cw^T bf16
  u16*   xb    = (u16*)(ws + 54661632);       // 50,331,648
  u16*   xbT   = (u16*)(ws + 104993280);      // 50,331,648 (dead after gram)
  u16*   R     = xbT;                         // aliases xbT
  // total ws use: 155,324,928 B

  convert_x<<<dim3(6, 64, 16), dim3(256), 0, stream>>>(x, xb, xbT);
  f32_to_bf16<<<dim3(72), dim3(256), 0, stream>>>(wp, wpb, (CC * CC) / 8);
  f32_to_bf16<<<dim3(72), dim3(256), 0, stream>>>(wq, wtopb, (CC * CC) / 8);
  f32_to_bf16<<<dim3(144), dim3(256), 0, stream>>>(wkv, wtopb + CC * CC,
                                                   (2 * CC * CC) / 8);
  transpose_cw<<<dim3(6, 6), dim3(256), 0, stream>>>(conv_w, cwTb);
  bias_fuse<<<dim3(288), dim3(256), 0, stream>>>(wq, bq, wkv, bkv, conv_b, bf_);
  // Wf[0:768] = wtop @ cw : C[o][c] = sum_m wtopb[o][m]*cwTb[c][m]
  gemm_f<u16, 0, 0, 0><<<dim3(18), dim3(256), 0, stream>>>(
      wtopb, cwTb, nullptr, Wf, 2 * CC, CC, CC, CC, 3, 6, 18,
      0, 0, 0, 0, 0);
  // UvT[c][j] = sum_m cwTb[c][m]*wkv_v[j][m]  (wkv_v = wtopb rows 768+)
  gemm_f<u16, 0, 0, 0><<<dim3(9), dim3(256), 0, stream>>>(
      cwTb, wtopb + 2 * CC * CC, nullptr, UvT, CC, CC, CC, CC, 3, 3, 9,
      0, 0, 0, 0, 0);
  colsum<<<dim3(24, 16), dim3(256), 0, stream>>>(xbT, sx);
  proj_sx<<<dim3(6, 16), dim3(128), 0, stream>>>(Wf, sx, P);
  // Gram partials (symmetric: 6 upper tiles only), split-K 4
  gemm_f<float, 0, 1><<<dim3(384), dim3(256), 0, stream>>>(
      xbT, xbT, nullptr, Gpart, CC, CC, NN, 1024, 3, 3, 24,
      (long)CC * NN, (long)CC * NN, 4L * 147456, 147456, 0);
  reduceG<<<dim3(576, 16), dim3(256), 0, stream>>>(Gpart, Gbf);
  // M1g[b] = Uq @ Gx_b
  gemm_f<u16, 0><<<dim3(144), dim3(256), 0, stream>>>(
      Wf, Gbf, nullptr, M1g, CC, CC, CC, CC, 3, 3, 9,
      0, 147456, 147456, 0, 0);
  s_softmax<<<dim3(128), dim3(256), 0, stream>>>(M1g, Wf, bf_, P, UvT, AUb, rb);
  // R[b] = AUb[b] @ xb_b^T + rbias (row-bias)
  gemm_f<u16, 2><<<dim3(1536), dim3(256), 0, stream>>>(
      AUb, xb, rb, R, CC, NN, CC, CC, 32, 3, 96,
      147456, (long)NN * CC, (long)NN * CC, 0, CC);
  // y = R @ wpb^T + bp
  gemm_f<float, 1><<<dim3(1536), dim3(256), 0, stream>>>(
      R, wpb, bp, y, BB * NN, CC, CC, CC, 3, 512, 1536,
      0, 0, 0, 0, 0);
}

// Round 9
// 225.100 us; speedup vs baseline: 1.0681x; 1.0177x over previous
//
#include <hip/hip_runtime.h>
#include <hip/hip_bf16.h>
#include <stdint.h>

#define DEVI static __device__ __forceinline__

typedef __attribute__((ext_vector_type(4))) float f32x4;
typedef __attribute__((ext_vector_type(8))) short bf16x8;
typedef unsigned short u16;
typedef unsigned int u32;
typedef unsigned long long u64;

// B=16, N=4096, C=384, H=8, D=48
#define BB 16
#define NN 4096
#define CC 384
#define HH 8
#define DD 48

DEVI u16 f2bf(float f) {
  union { float f; u32 u; } c; c.f = f;
  u32 u = c.u;
  u32 r = (u + 0x7FFFu + ((u >> 16) & 1u)) >> 16;
  return (u16)r;
}
DEVI float bf2f(u16 h) {
  union { float f; u32 u; } c; c.u = ((u32)h) << 16;
  return c.f;
}
DEVI void stage8(u16* dst, const float* src) {
  const f32x4 a = *(const f32x4*)(src);
  const f32x4 b = *(const f32x4*)(src + 4);
  union { bf16x8 v; u16 u[8]; } o;
  o.u[0] = f2bf(a[0]); o.u[1] = f2bf(a[1]); o.u[2] = f2bf(a[2]); o.u[3] = f2bf(a[3]);
  o.u[4] = f2bf(b[0]); o.u[5] = f2bf(b[1]); o.u[6] = f2bf(b[2]); o.u[7] = f2bf(b[3]);
  *(bf16x8*)dst = o.v;
}

typedef const __attribute__((address_space(1))) void* gas_ptr;
typedef __attribute__((address_space(3))) void* las_ptr;
DEVI void gload16(const void* g, void* l) {
  __builtin_amdgcn_global_load_lds((gas_ptr)g, (las_ptr)l, 16, 0, 0);
}

// ============================================================================
// fp32 -> bf16 bulk convert
// ============================================================================
__global__ __launch_bounds__(256)
void f32_to_bf16(const float* __restrict__ in, u16* __restrict__ out, int n8) {
  const int i = blockIdx.x * 256 + threadIdx.x;
  if (i >= n8) return;
  u16 tmp[8];
  stage8(tmp, in + (size_t)i * 8);
  *(bf16x8*)(out + (size_t)i * 8) = *(bf16x8*)tmp;
}

// ============================================================================
// convert_x v2: x f32 [B,N,C] -> xb bf16 (direct from regs) and xbT bf16
// [B,C,N] via u32 n-pair packed LDS transpose (all 32-bit LDS ops, <=2-way).
// ============================================================================
__global__ __launch_bounds__(256)
void convert_x(const float* __restrict__ x, u16* __restrict__ xb,
               u16* __restrict__ xbT) {
  __shared__ u32 LtT[64 * 33];        // [c][n-pair], pad 1 -> 8448 B
  const int ct = blockIdx.x, nt = blockIdx.y, b = blockIdx.z;
  const int t = threadIdx.x;
  const int n0 = nt * 64, c0 = ct * 64;
  const int cl = (t & 15) * 4;
  const int np = t >> 4;
#pragma unroll
  for (int pass = 0; pass < 2; ++pass) {
    const int w = np + pass * 16;
    const int n = w * 2;
    const float* s0 = &x[((size_t)(b * NN + n0 + n)) * CC + c0 + cl];
    const f32x4 a = *(const f32x4*)s0;
    const f32x4 bv = *(const f32x4*)(s0 + CC);
    const u16 a0 = f2bf(a[0]), a1 = f2bf(a[1]), a2 = f2bf(a[2]), a3 = f2bf(a[3]);
    const u16 b0 = f2bf(bv[0]), b1 = f2bf(bv[1]), b2 = f2bf(bv[2]), b3 = f2bf(bv[3]);
    *(u64*)&xb[((size_t)(b * NN + n0 + n)) * CC + c0 + cl] =
        (u64)a0 | ((u64)a1 << 16) | ((u64)a2 << 32) | ((u64)a3 << 48);
    *(u64*)&xb[((size_t)(b * NN + n0 + n + 1)) * CC + c0 + cl] =
        (u64)b0 | ((u64)b1 << 16) | ((u64)b2 << 32) | ((u64)b3 << 48);
    LtT[(cl + 0) * 33 + w] = (u32)a0 | ((u32)b0 << 16);
    LtT[(cl + 1) * 33 + w] = (u32)a1 | ((u32)b1 << 16);
    LtT[(cl + 2) * 33 + w] = (u32)a2 | ((u32)b2 << 16);
    LtT[(cl + 3) * 33 + w] = (u32)a3 | ((u32)b3 << 16);
  }
  __syncthreads();
#pragma unroll
  for (int pass = 0; pass < 2; ++pass) {
    const int v = pass * 256 + t;
    const int c = v >> 3, ng = v & 7;
    union { bf16x8 o; u32 q[4]; } u;
#pragma unroll
    for (int r = 0; r < 4; ++r) u.q[r] = LtT[c * 33 + ng * 4 + r];
    *(bf16x8*)&xbT[((size_t)(b * CC + c0 + c)) * NN + n0 + ng * 8] = u.o;
  }
}

// ============================================================================
// cw (f32 [m=384][c=384]) -> cwT bf16 [c][m]
// ============================================================================
__global__ __launch_bounds__(256)
void transpose_cw(const float* __restrict__ cw, u16* __restrict__ cwT) {
  __shared__ u32 LtT[64 * 33];
  const int mt = blockIdx.x, ct = blockIdx.y;
  const int t = threadIdx.x;
  const int m0 = mt * 64, c0 = ct * 64;
  const int cl = (t & 15) * 4;
  const int mp = t >> 4;
#pragma unroll
  for (int pass = 0; pass < 2; ++pass) {
    const int w = mp + pass * 16;
    const int m = w * 2;
    const float* s0 = &cw[(size_t)(m0 + m) * CC + c0 + cl];
    const f32x4 a = *(const f32x4*)s0;
    const f32x4 bv = *(const f32x4*)(s0 + CC);
#pragma unroll
    for (int i = 0; i < 4; ++i)
      LtT[(cl + i) * 33 + w] = (u32)f2bf(a[i]) | ((u32)f2bf(bv[i]) << 16);
  }
  __syncthreads();
#pragma unroll
  for (int pass = 0; pass < 2; ++pass) {
    const int v = pass * 256 + t;
    const int c = v >> 3, mg = v & 7;
    union { bf16x8 o; u32 q[4]; } u;
#pragma unroll
    for (int r = 0; r < 4; ++r) u.q[r] = LtT[c * 33 + mg * 4 + r];
    *(bf16x8*)&cwT[(size_t)(c0 + c) * CC + m0 + mg * 8] = u.o;
  }
}

// ============================================================================
// bias_fuse: bf_[o] = btop[o] + sum_m wtop[o][m]*cb[m]  (one wave per o)
// ============================================================================
__global__ __launch_bounds__(256)
void bias_fuse(const float* __restrict__ wq, const float* __restrict__ bq,
               const float* __restrict__ wkv, const float* __restrict__ bkv,
               const float* __restrict__ cb, float* __restrict__ bf_) {
  const int o = blockIdx.x * 4 + (threadIdx.x >> 6);
  const int lane = threadIdx.x & 63;
  const float* wrow;
  float b0;
  if (o < CC) { wrow = wq + (size_t)o * CC;        b0 = bq[o]; }
  else        { wrow = wkv + (size_t)(o - CC) * CC; b0 = bkv[o - CC]; }
  float s = 0.f;
  for (int m = lane; m < CC; m += 64) s += wrow[m] * cb[m];
#pragma unroll
  for (int off = 32; off; off >>= 1) s += __shfl_xor(s, off, 64);
  if (lane == 0) bf_[o] = b0 + s;
}

// ============================================================================
// colsum: sx[b][c] = sum_n xbT[b][c][n]
// ============================================================================
__global__ __launch_bounds__(256)
void colsum(const u16* __restrict__ xbT, float* __restrict__ sx) {
  const int b = blockIdx.y, c = blockIdx.x * 16 + (threadIdx.x >> 4);
  const int sl = threadIdx.x & 15;
  const u16* src = xbT + ((size_t)(b * CC + c)) * NN + sl * 256;
  float s = 0.f;
  for (int i = 0; i < 32; ++i) {
    const bf16x8 v = *(const bf16x8*)(src + i * 8);
#pragma unroll
    for (int r = 0; r < 8; ++r) s += bf2f((u16)v[r]);
  }
#pragma unroll
  for (int m = 1; m < 16; m <<= 1) s += __shfl_xor(s, m, 64);
  if (sl == 0) sx[b * CC + c] = s;
}

// ============================================================================
// proj_sx: P[b][o] = sum_c Wf[o][c] * sx[b][c], o<768
// ============================================================================
__global__ __launch_bounds__(128)
void proj_sx(const u16* __restrict__ Wf, const float* __restrict__ sx,
             float* __restrict__ P) {
  __shared__ float sl[CC];
  const int b = blockIdx.y, o = blockIdx.x * 128 + threadIdx.x;
  for (int i = threadIdx.x; i < CC; i += 128) sl[i] = sx[b * CC + i];
  __syncthreads();
  float acc = 0.f;
  const u16* wr = Wf + (size_t)o * CC;
  for (int c8 = 0; c8 < CC; c8 += 8) {
    const bf16x8 w = *(const bf16x8*)(wr + c8);
#pragma unroll
    for (int r = 0; r < 8; ++r) acc += bf2f((u16)w[r]) * sl[c8 + r];
  }
  P[b * 768 + o] = acc;
}

// ============================================================================
// Generic GEMM: C[M,N](+p partials) = A[M,K-slice] @ W[N,K-slice]^T (+bias)
// R6 dbuf structure (issue-early / wait-late = minimum 2-phase pipeline).
// T2 both-sides swizzle. fp32 epilogue: DIRECT scalar stores (R8's LDS
// restage cost ~+23us: half-active waves + 4 barriers > coalescing gain).
// TRI: 6 upper tiles. SWZ: XCD swizzle (grid%8==0 only).
// ============================================================================
template<typename OT, int BIASMODE, int TRI = 0, int SWZ = 1>
__global__ __launch_bounds__(256)
void gemm_f(const u16* __restrict__ A, const u16* __restrict__ W,
            const float* __restrict__ bias, OT* __restrict__ C,
            int M, int N, int K, int klen, int nbn, int nbm, int tpb,
            long sA, long sW, long sC, long sCp, long sBias) {
  constexpr int BK = 64;
  __shared__ __align__(16) u16 smem[32768];   // 64 KB: 2 x (As 8192 | Bs 8192)

  const int nx = gridDim.x;
  const int lin = blockIdx.x;
  const int lin2 = SWZ ? (lin & 7) * (nx >> 3) + (lin >> 3) : lin;
  const int b = lin2 / tpb;
  int t2 = lin2 % tpb;
  int bn, bm, p;
  if constexpr (TRI) {
    const int tl = t2 % 6; p = t2 / 6;
    bm = tl < 3 ? 0 : (tl < 5 ? 1 : 2);
    bn = tl < 3 ? tl : (tl < 5 ? tl - 2 : 2);
  } else {
    bn = t2 % nbn; t2 /= nbn;
    bm = t2 % nbm;
    p = t2 / nbm;
  }
  A += (size_t)b * sA; W += (size_t)b * sW;
  C += (size_t)b * sC + (size_t)p * sCp;
  if (BIASMODE) bias += (size_t)b * sBias;

  const int t = threadIdx.x;
  const int wid = t >> 6, lane = t & 63;
  const int wr = wid >> 1, wc = wid & 1;
  const int row0 = bm * 128, col0 = bn * 128;
  const int lrow = lane & 15;
  const int lswz = (lane & 7) << 3;
  const int kstart = p * klen;

  const int arow = t >> 3;
  const int scol = ((t & 7) ^ ((t >> 3) & 7)) * 8;   // inverse-swizzled source
  const u16* Ag = A + (size_t)(row0 + arow) * K + scol;
  const u16* Wg = W + (size_t)(col0 + arow) * K + scol;

  f32x4 acc[4][4] = {};
  const int NT = klen >> 6;

  auto stage = [&](int buf, int kt) {
    u16* Al = smem + buf * 16384 + t * 8;
    u16* Bl = smem + buf * 16384 + 8192 + t * 8;
    const int k0 = kstart + kt * BK;
#pragma unroll
    for (int it = 0; it < 4; ++it) {
      gload16(Ag + (size_t)(it * 32) * K + k0, Al + it * 2048);
      gload16(Wg + (size_t)(it * 32) * K + k0, Bl + it * 2048);
    }
  };

  stage(0, 0);
  __syncthreads();                 // drain tile 0
  int cur = 0;
  for (int kt = 0; kt < NT; ++kt) {
    if (kt + 1 < NT) stage(cur ^ 1, kt + 1);     // issue-early (overlaps MFMA)
    const u16* As = smem + cur * 16384;
    const u16* Bs = smem + cur * 16384 + 8192;
#pragma unroll
    for (int kk = 0; kk < 2; ++kk) {
      const int lk = (kk * 32 + (lane >> 4) * 8) ^ lswz;
      bf16x8 af[4], bf[4];
#pragma unroll
      for (int i = 0; i < 4; ++i)
        af[i] = *(const bf16x8*)&As[(wr * 64 + i * 16 + lrow) * BK + lk];
#pragma unroll
      for (int j = 0; j < 4; ++j)
        bf[j] = *(const bf16x8*)&Bs[(wc * 64 + j * 16 + lrow) * BK + lk];
#pragma unroll
      for (int i = 0; i < 4; ++i)
#pragma unroll
        for (int j = 0; j < 4; ++j)
          acc[i][j] = __builtin_amdgcn_mfma_f32_16x16x32_bf16(af[i], bf[j], acc[i][j], 0, 0, 0);
    }
    __syncthreads();               // wait-late: drains next tile's loads + LDS reads
    cur ^= 1;
  }

  const int lr = (lane >> 4) * 4;
  if constexpr (sizeof(OT) == 2) {
    u16* Ct = smem;                 // [128][132] bf16 = 33792 B
#pragma unroll
    for (int i = 0; i < 4; ++i)
#pragma unroll
      for (int j = 0; j < 4; ++j) {
        const int ccol = wc * 64 + j * 16 + lrow;
        float bv = 0.f;
        if constexpr (BIASMODE == 1) bv = bias[col0 + ccol];
#pragma unroll
        for (int r = 0; r < 4; ++r) {
          const int rrow = wr * 64 + i * 16 + lr + r;
          float b2 = bv;
          if constexpr (BIASMODE == 2) b2 = bias[row0 + rrow];
          Ct[rrow * 132 + ccol] = f2bf(acc[i][j][r] + b2);
        }
      }
    __syncthreads();
#pragma unroll
    for (int it = 0; it < 8; ++it) {
      const int id = it * 256 + t;
      const int row = id >> 4, c16 = (id & 15) * 8;
      *(bf16x8*)((u16*)C + (size_t)(row0 + row) * N + col0 + c16) =
          *(const bf16x8*)&Ct[row * 132 + c16];
    }
  } else {
    const int orow = row0 + wr * 64, ocol = col0 + wc * 64;
#pragma unroll
    for (int i = 0; i < 4; ++i)
#pragma unroll
      for (int j = 0; j < 4; ++j) {
        const int cc2 = ocol + j * 16 + lrow;
        float bv = 0.f;
        if constexpr (BIASMODE == 1) bv = bias[cc2];
#pragma unroll
        for (int r = 0; r < 4; ++r) {
          const int rr = orow + i * 16 + lr + r;
          float b2 = bv;
          if constexpr (BIASMODE == 2) b2 = bias[rr];
          C[(size_t)rr * N + cc2] = acc[i][j][r] + b2;
        }
      }
  }
}

// ============================================================================
// reduceG: Gbf[b][i][j] = bf16( sum_p Gpart[b][p][upper(i,j)] )  (symmetric)
// ============================================================================
__global__ __launch_bounds__(256)
void reduceG(const float* __restrict__ Gp, u16* __restrict__ Gbf) {
  const int b = blockIdx.y;
  const int e = blockIdx.x * 256 + threadIdx.x;
  const int i = e / CC, j = e % CC;
  const int ee = (i <= j) ? e : (j * CC + i);
  const float* s = Gp + (size_t)b * 4 * 147456 + ee;
  Gbf[(size_t)b * 147456 + e] =
      f2bf(s[0] + s[147456] + s[2 * 147456] + s[3 * 147456]);
}

// ============================================================================
// s_softmax: per (b,h): S = M1_h @ Uk_h^T + rank-1 terms, *N^-0.5, softmax;
// AU = attn @ Uv_h -> AUb rows (i*8+h); rbias = attn @ bv'
// ============================================================================
__global__ __launch_bounds__(256)
void s_softmax(const u16* __restrict__ M1g, const u16* __restrict__ Wf,
               const float* __restrict__ bf_, const float* __restrict__ P,
               const u16* __restrict__ UvT, u16* __restrict__ AUb,
               float* __restrict__ rbias) {
  __shared__ float Sf[48 * 52];
  __shared__ __align__(16) u16 att[48 * 56];
  const int bh = blockIdx.x, b = bh >> 3, h = bh & 7;
  const int t = threadIdx.x, wid = t >> 6, lane = t & 63;
  const int lrow = lane & 15, lkq = lane >> 4;

  if (wid < 3) {
    f32x4 acc[3] = {};
    const u16* Arow = M1g + (size_t)b * 147456 + (size_t)(h * 48 + wid * 16 + lrow) * CC;
    const u16* Brow = Wf + (size_t)(CC + h * 48) * CC;    // Uk
    for (int ks = 0; ks < 12; ++ks) {
      const int k = ks * 32 + lkq * 8;
      const bf16x8 af = *(const bf16x8*)(Arow + k);
#pragma unroll
      for (int j = 0; j < 3; ++j) {
        const bf16x8 bfr = *(const bf16x8*)(Brow + (size_t)(j * 16 + lrow) * CC + k);
        acc[j] = __builtin_amdgcn_mfma_f32_16x16x32_bf16(af, bfr, acc[j], 0, 0, 0);
      }
    }
    const int lr = lkq * 4;
#pragma unroll
    for (int j = 0; j < 3; ++j)
#pragma unroll
      for (int r = 0; r < 4; ++r)
        Sf[(wid * 16 + lr + r) * 52 + j * 16 + lrow] = acc[j][r];
  }
  __syncthreads();

  if (t < 48) {
    const float bi = bf_[h * 48 + t];
    const float pq = P[b * 768 + h * 48 + t];
    float row[48];
    float mx = -1e30f;
#pragma unroll
    for (int j = 0; j < 48; ++j) {
      const float g = bf_[CC + h * 48 + j];
      const float pk = P[b * 768 + CC + h * 48 + j];
      const float s = (Sf[t * 52 + j] + bi * pk + pq * g + 4096.f * bi * g) * 0.015625f;
      row[j] = s;
      mx = fmaxf(mx, s);
    }
    float sum = 0.f;
#pragma unroll
    for (int j = 0; j < 48; ++j) { row[j] = __expf(row[j] - mx); sum += row[j]; }
    const float inv = 1.f / sum;
    float rb = 0.f;
#pragma unroll
    for (int j = 0; j < 48; ++j) {
      const float a = row[j] * inv;
      att[t * 56 + j] = f2bf(a);
      rb += a * bf_[2 * CC + h * 48 + j];
    }
#pragma unroll
    for (int j = 48; j < 56; ++j) att[t * 56 + j] = 0;
    rbias[b * CC + t * 8 + h] = rb;
  }
  __syncthreads();

  f32x4 acc[3][6] = {};
  const u16* Vbase = UvT + h * 48;
  const bf16x8 z = {};
#pragma unroll
  for (int kk = 0; kk < 2; ++kk) {
    const int k = kk * 32 + lkq * 8;
    bf16x8 af[3];
#pragma unroll
    for (int i = 0; i < 3; ++i) {
      af[i] = *(const bf16x8*)&att[(i * 16 + lrow) * 56 + k];
      if (k >= 48) af[i] = z;
    }
#pragma unroll
    for (int ct = 0; ct < 6; ++ct) {
      const int c = wid * 96 + ct * 16 + lrow;
      bf16x8 bfr = *(const bf16x8*)(Vbase + (size_t)c * CC + k);
      if (k >= 48) bfr = z;
#pragma unroll
      for (int i = 0; i < 3; ++i)
        acc[i][ct] = __builtin_amdgcn_mfma_f32_16x16x32_bf16(af[i], bfr, acc[i][ct], 0, 0, 0);
    }
  }
  const int lr = lkq * 4;
#pragma unroll
  for (int i = 0; i < 3; ++i)
#pragma unroll
    for (int ct = 0; ct < 6; ++ct) {
      const int c = wid * 96 + ct * 16 + lrow;
#pragma unroll
      for (int r = 0; r < 4; ++r) {
        const int ii = i * 16 + lr + r;
        AUb[(size_t)b * 147456 + (size_t)(ii * 8 + h) * CC + c] = f2bf(acc[i][ct][r]);
      }
    }
}

// ============================================================================
extern "C" void kernel_launch(void* const* d_in, const int* in_sizes, int n_in,
                              void* d_out, int out_size, void* d_ws, size_t ws_size,
                              hipStream_t stream) {
  const float* x      = (const float*)d_in[0];
  const float* conv_w = (const float*)d_in[1];
  const float* conv_b = (const float*)d_in[2];
  const float* wq     = (const float*)d_in[3];
  const float* bq     = (const float*)d_in[4];
  const float* wkv    = (const float*)d_in[5];
  const float* bkv    = (const float*)d_in[6];
  const float* wp     = (const float*)d_in[7];
  const float* bp     = (const float*)d_in[8];
  float* y = (float*)d_out;

  char* ws = (char*)d_ws;
  u16*   Wf    = (u16*)(ws + 0);              //   884,736 (rows 768+ unused)
  float* bf_   = (float*)(ws + 884736);       //     4,608
  u16*   wpb   = (u16*)(ws + 889344);         //   294,912
  u16*   UvT   = (u16*)(ws + 1184256);        //   294,912
  float* sx    = (float*)(ws + 1479168);      //    24,576
  float* P     = (float*)(ws + 1503744);      //    49,152
  float* rb    = (float*)(ws + 1552896);      //    24,576
  u16*   M1g   = (u16*)(ws + 1577472);        // 4,718,592
  u16*   Gbf   = (u16*)(ws + 6296064);        // 4,718,592
  u16*   AUb   = (u16*)(ws + 11014656);       // 4,718,592
  float* Gpart = (float*)(ws + 15733248);     // 37,748,736
  u16*   wtopb = (u16*)(ws + 53481984);       //   884,736  [wq;wkv] bf16
  u16*   cwTb  = (u16*)(ws + 54366720);       //   294,912  cw^T bf16
  u16*   xb    = (u16*)(ws + 54661632);       // 50,331,648
  u16*   xbT   = (u16*)(ws + 104993280);      // 50,331,648 (dead after gram)
  u16*   R     = xbT;                         // aliases xbT
  // total ws use: 155,324,928 B

  convert_x<<<dim3(6, 64, 16), dim3(256), 0, stream>>>(x, xb, xbT);
  f32_to_bf16<<<dim3(72), dim3(256), 0, stream>>>(wp, wpb, (CC * CC) / 8);
  f32_to_bf16<<<dim3(72), dim3(256), 0, stream>>>(wq, wtopb, (CC * CC) / 8);
  f32_to_bf16<<<dim3(144), dim3(256), 0, stream>>>(wkv, wtopb + CC * CC,
                                                   (2 * CC * CC) / 8);
  transpose_cw<<<dim3(6, 6), dim3(256), 0, stream>>>(conv_w, cwTb);
  bias_fuse<<<dim3(288), dim3(256), 0, stream>>>(wq, bq, wkv, bkv, conv_b, bf_);
  // Wf[0:768] = wtop @ cw : C[o][c] = sum_m wtopb[o][m]*cwTb[c][m]
  gemm_f<u16, 0, 0, 0><<<dim3(18), dim3(256), 0, stream>>>(
      wtopb, cwTb, nullptr, Wf, 2 * CC, CC, CC, CC, 3, 6, 18,
      0, 0, 0, 0, 0);
  // UvT[c][j] = sum_m cwTb[c][m]*wkv_v[j][m]  (wkv_v = wtopb rows 768+)
  gemm_f<u16, 0, 0, 0><<<dim3(9), dim3(256), 0, stream>>>(
      cwTb, wtopb + 2 * CC * CC, nullptr, UvT, CC, CC, CC, CC, 3, 3, 9,
      0, 0, 0, 0, 0);
  colsum<<<dim3(24, 16), dim3(256), 0, stream>>>(xbT, sx);
  proj_sx<<<dim3(6, 16), dim3(128), 0, stream>>>(Wf, sx, P);
  // Gram partials (symmetric: 6 upper tiles only), split-K 4
  gemm_f<float, 0, 1><<<dim3(384), dim3(256), 0, stream>>>(
      xbT, xbT, nullptr, Gpart, CC, CC, NN, 1024, 3, 3, 24,
      (long)CC * NN, (long)CC * NN, 4L * 147456, 147456, 0);
  reduceG<<<dim3(576, 16), dim3(256), 0, stream>>>(Gpart, Gbf);
  // M1g[b] = Uq @ Gx_b
  gemm_f<u16, 0><<<dim3(144), dim3(256), 0, stream>>>(
      Wf, Gbf, nullptr, M1g, CC, CC, CC, CC, 3, 3, 9,
      0, 147456, 147456, 0, 0);
  s_softmax<<<dim3(128), dim3(256), 0, stream>>>(M1g, Wf, bf_, P, UvT, AUb, rb);
  // R[b] = AUb[b] @ xb_b^T + rbias (row-bias)
  gemm_f<u16, 2><<<dim3(1536), dim3(256), 0, stream>>>(
      AUb, xb, rb, R, CC, NN, CC, CC, 32, 3, 96,
      147456, (long)NN * CC, (long)NN * CC, 0, CC);
  // y = R @ wpb^T + bp
  gemm_f<float, 1><<<dim3(1536), dim3(256), 0, stream>>>(
      R, wpb, bp, y, BB * NN, CC, CC, CC, 3, 512, 1536,
      0, 0, 0, 0, 0);
}

// Round 10
// 223.187 us; speedup vs baseline: 1.0773x; 1.0086x over previous
//
#include <hip/hip_runtime.h>
#include <hip/hip_bf16.h>
#include <stdint.h>

#define DEVI static __device__ __forceinline__

typedef __attribute__((ext_vector_type(4))) float f32x4;
typedef __attribute__((ext_vector_type(4))) unsigned int u32x4;
typedef __attribute__((ext_vector_type(8))) short bf16x8;
typedef unsigned short u16;
typedef unsigned int u32;
typedef unsigned long long u64;

// B=16, N=4096, C=384, H=8, D=48
#define BB 16
#define NN 4096
#define CC 384
#define HH 8
#define DD 48

DEVI u16 f2bf(float f) {
  union { float f; u32 u; } c; c.f = f;
  u32 u = c.u;
  u32 r = (u + 0x7FFFu + ((u >> 16) & 1u)) >> 16;
  return (u16)r;
}
DEVI float bf2f(u16 h) {
  union { float f; u32 u; } c; c.u = ((u32)h) << 16;
  return c.f;
}
DEVI void stage8(u16* dst, const float* src) {
  const f32x4 a = *(const f32x4*)(src);
  const f32x4 b = *(const f32x4*)(src + 4);
  union { bf16x8 v; u16 u[8]; } o;
  o.u[0] = f2bf(a[0]); o.u[1] = f2bf(a[1]); o.u[2] = f2bf(a[2]); o.u[3] = f2bf(a[3]);
  o.u[4] = f2bf(b[0]); o.u[5] = f2bf(b[1]); o.u[6] = f2bf(b[2]); o.u[7] = f2bf(b[3]);
  *(bf16x8*)dst = o.v;
}

typedef const __attribute__((address_space(1))) void* gas_ptr;
typedef __attribute__((address_space(3))) void* las_ptr;
DEVI void gload16(const void* g, void* l) {
  __builtin_amdgcn_global_load_lds((gas_ptr)g, (las_ptr)l, 16, 0, 0);
}

// ============================================================================
// fp32 -> bf16 bulk convert
// ============================================================================
__global__ __launch_bounds__(256)
void f32_to_bf16(const float* __restrict__ in, u16* __restrict__ out, int n8) {
  const int i = blockIdx.x * 256 + threadIdx.x;
  if (i >= n8) return;
  u16 tmp[8];
  stage8(tmp, in + (size_t)i * 8);
  *(bf16x8*)(out + (size_t)i * 8) = *(bf16x8*)tmp;
}

// ============================================================================
// convert_x v3: tile 64c x 128n. All global ops 16B. 8 loads issued up-front
// (128B/thread in flight). LDS u32 n-pair transpose, npair XOR-swizzled by
// c-octet -> phase1 writes 2-way max, phase2 = ONE ds_read_b128 per 16B out.
// xbT writes 256B contiguous per 16-lane group (was 128B @ 8KB stride).
// ============================================================================
__global__ __launch_bounds__(256)
void convert_x(const float* __restrict__ x, u16* __restrict__ xb,
               u16* __restrict__ xbT) {
  __shared__ u32 LtT[64 * 68];        // [c][npair(swizzled)] = 17408 B
  const int ct = blockIdx.x, nt = blockIdx.y, b = blockIdx.z;
  const int t = threadIdx.x;
  const int n0 = nt * 128, c0 = ct * 64;
  const int coct = t & 7, c = coct * 8;
  const int q = t >> 3;               // 0..31

  f32x4 v[2][4];
#pragma unroll
  for (int p = 0; p < 2; ++p) {       // all 8 loads issued before any use
    const int n = 2 * (p * 32 + q);
    const float* s0 = &x[((size_t)(b * NN + n0 + n)) * CC + c0 + c];
    v[p][0] = *(const f32x4*)s0;
    v[p][1] = *(const f32x4*)(s0 + 4);
    v[p][2] = *(const f32x4*)(s0 + CC);
    v[p][3] = *(const f32x4*)(s0 + CC + 4);
  }
#pragma unroll
  for (int p = 0; p < 2; ++p) {
    const int npair = p * 32 + q;
    const int n = 2 * npair;
    union { bf16x8 o; u16 e[8]; } ua, ub;
#pragma unroll
    for (int r = 0; r < 4; ++r) {
      ua.e[r] = f2bf(v[p][0][r]); ua.e[r + 4] = f2bf(v[p][1][r]);
      ub.e[r] = f2bf(v[p][2][r]); ub.e[r + 4] = f2bf(v[p][3][r]);
    }
    *(bf16x8*)&xb[((size_t)(b * NN + n0 + n)) * CC + c0 + c] = ua.o;
    *(bf16x8*)&xb[((size_t)(b * NN + n0 + n + 1)) * CC + c0 + c] = ub.o;
    const int npw = npair ^ (coct << 3);     // bank swizzle (bijective)
#pragma unroll
    for (int i = 0; i < 8; ++i)
      LtT[(c + i) * 68 + npw] = (u32)ua.e[i] | ((u32)ub.e[i] << 16);
  }
  __syncthreads();
#pragma unroll
  for (int p = 0; p < 4; ++p) {
    const int id = p * 256 + t;
    const int cc2 = id >> 4, ng = id & 15;
    const int co2 = (cc2 >> 3) & 7;
    union { u32x4 q4; bf16x8 o; } u;
    u.q4 = *(const u32x4*)&LtT[cc2 * 68 + ((ng * 4) ^ (co2 << 3))];
    *(bf16x8*)&xbT[((size_t)(b * CC + c0 + cc2)) * NN + n0 + ng * 8] = u.o;
  }
}

// ============================================================================
// cw (f32 [m=384][c=384]) -> cwT bf16 [c][m]  (small; v2 scheme kept)
// ============================================================================
__global__ __launch_bounds__(256)
void transpose_cw(const float* __restrict__ cw, u16* __restrict__ cwT) {
  __shared__ u32 LtT[64 * 33];
  const int mt = blockIdx.x, ct = blockIdx.y;
  const int t = threadIdx.x;
  const int m0 = mt * 64, c0 = ct * 64;
  const int cl = (t & 15) * 4;
  const int mp = t >> 4;
#pragma unroll
  for (int pass = 0; pass < 2; ++pass) {
    const int w = mp + pass * 16;
    const int m = w * 2;
    const float* s0 = &cw[(size_t)(m0 + m) * CC + c0 + cl];
    const f32x4 a = *(const f32x4*)s0;
    const f32x4 bv = *(const f32x4*)(s0 + CC);
#pragma unroll
    for (int i = 0; i < 4; ++i)
      LtT[(cl + i) * 33 + w] = (u32)f2bf(a[i]) | ((u32)f2bf(bv[i]) << 16);
  }
  __syncthreads();
#pragma unroll
  for (int pass = 0; pass < 2; ++pass) {
    const int v = pass * 256 + t;
    const int c = v >> 3, mg = v & 7;
    union { bf16x8 o; u32 q[4]; } u;
#pragma unroll
    for (int r = 0; r < 4; ++r) u.q[r] = LtT[c * 33 + mg * 4 + r];
    *(bf16x8*)&cwT[(size_t)(c0 + c) * CC + m0 + mg * 8] = u.o;
  }
}

// ============================================================================
// bias_fuse: bf_[o] = btop[o] + sum_m wtop[o][m]*cb[m]  (one wave per o)
// ============================================================================
__global__ __launch_bounds__(256)
void bias_fuse(const float* __restrict__ wq, const float* __restrict__ bq,
               const float* __restrict__ wkv, const float* __restrict__ bkv,
               const float* __restrict__ cb, float* __restrict__ bf_) {
  const int o = blockIdx.x * 4 + (threadIdx.x >> 6);
  const int lane = threadIdx.x & 63;
  const float* wrow;
  float b0;
  if (o < CC) { wrow = wq + (size_t)o * CC;        b0 = bq[o]; }
  else        { wrow = wkv + (size_t)(o - CC) * CC; b0 = bkv[o - CC]; }
  float s = 0.f;
  for (int m = lane; m < CC; m += 64) s += wrow[m] * cb[m];
#pragma unroll
  for (int off = 32; off; off >>= 1) s += __shfl_xor(s, off, 64);
  if (lane == 0) bf_[o] = b0 + s;
}

// ============================================================================
// colsum: sx[b][c] = sum_n xbT[b][c][n]
// ============================================================================
__global__ __launch_bounds__(256)
void colsum(const u16* __restrict__ xbT, float* __restrict__ sx) {
  const int b = blockIdx.y, c = blockIdx.x * 16 + (threadIdx.x >> 4);
  const int sl = threadIdx.x & 15;
  const u16* src = xbT + ((size_t)(b * CC + c)) * NN + sl * 256;
  float s = 0.f;
  for (int i = 0; i < 32; ++i) {
    const bf16x8 v = *(const bf16x8*)(src + i * 8);
#pragma unroll
    for (int r = 0; r < 8; ++r) s += bf2f((u16)v[r]);
  }
#pragma unroll
  for (int m = 1; m < 16; m <<= 1) s += __shfl_xor(s, m, 64);
  if (sl == 0) sx[b * CC + c] = s;
}

// ============================================================================
// proj_sx: P[b][o] = sum_c Wf[o][c] * sx[b][c], o<768
// ============================================================================
__global__ __launch_bounds__(128)
void proj_sx(const u16* __restrict__ Wf, const float* __restrict__ sx,
             float* __restrict__ P) {
  __shared__ float sl[CC];
  const int b = blockIdx.y, o = blockIdx.x * 128 + threadIdx.x;
  for (int i = threadIdx.x; i < CC; i += 128) sl[i] = sx[b * CC + i];
  __syncthreads();
  float acc = 0.f;
  const u16* wr = Wf + (size_t)o * CC;
  for (int c8 = 0; c8 < CC; c8 += 8) {
    const bf16x8 w = *(const bf16x8*)(wr + c8);
#pragma unroll
    for (int r = 0; r < 8; ++r) acc += bf2f((u16)w[r]) * sl[c8 + r];
  }
  P[b * 768 + o] = acc;
}

// ============================================================================
// Generic GEMM: C[M,N](+p partials) = A[M,K-slice] @ W[N,K-slice]^T (+bias)
// 512 threads / 8 waves (wave tile 64x32, acc 4x2): 2 blocks/CU -> 4 waves/
// SIMD (was 2) to hide the vmcnt-drain barrier. Dbuf issue-early/wait-late,
// T2 both-sides swizzle. TRI: 6 upper tiles. SWZ: XCD swizzle (grid%8==0).
// ============================================================================
template<typename OT, int BIASMODE, int TRI = 0, int SWZ = 1>
__global__ __launch_bounds__(512)
void gemm_f(const u16* __restrict__ A, const u16* __restrict__ W,
            const float* __restrict__ bias, OT* __restrict__ C,
            int M, int N, int K, int klen, int nbn, int nbm, int tpb,
            long sA, long sW, long sC, long sCp, long sBias) {
  constexpr int BK = 64;
  __shared__ __align__(16) u16 smem[32768];   // 64 KB: 2 x (As 8192 | Bs 8192)

  const int nx = gridDim.x;
  const int lin = blockIdx.x;
  const int lin2 = SWZ ? (lin & 7) * (nx >> 3) + (lin >> 3) : lin;
  const int b = lin2 / tpb;
  int t2 = lin2 % tpb;
  int bn, bm, p;
  if constexpr (TRI) {
    const int tl = t2 % 6; p = t2 / 6;
    bm = tl < 3 ? 0 : (tl < 5 ? 1 : 2);
    bn = tl < 3 ? tl : (tl < 5 ? tl - 2 : 2);
  } else {
    bn = t2 % nbn; t2 /= nbn;
    bm = t2 % nbm;
    p = t2 / nbm;
  }
  A += (size_t)b * sA; W += (size_t)b * sW;
  C += (size_t)b * sC + (size_t)p * sCp;
  if (BIASMODE) bias += (size_t)b * sBias;

  const int t = threadIdx.x;
  const int wid = t >> 6, lane = t & 63;
  const int wr = wid >> 2, wc = wid & 3;        // 2 x 4 wave grid, 64x32 each
  const int row0 = bm * 128, col0 = bn * 128;
  const int lrow = lane & 15;
  const int lswz = (lane & 7) << 3;
  const int kstart = p * klen;

  const int arow = t >> 3;                       // 0..63
  const int scol = ((t & 7) ^ ((t >> 3) & 7)) * 8;   // inverse-swizzled source
  const u16* Ag = A + (size_t)(row0 + arow) * K + scol;
  const u16* Wg = W + (size_t)(col0 + arow) * K + scol;

  f32x4 acc[4][2] = {};
  const int NT = klen >> 6;

  auto stage = [&](int buf, int kt) {
    u16* Al = smem + buf * 16384 + t * 8;
    u16* Bl = smem + buf * 16384 + 8192 + t * 8;
    const int k0 = kstart + kt * BK;
#pragma unroll
    for (int it = 0; it < 2; ++it) {
      gload16(Ag + (size_t)(it * 64) * K + k0, Al + it * 4096);
      gload16(Wg + (size_t)(it * 64) * K + k0, Bl + it * 4096);
    }
  };

  stage(0, 0);
  __syncthreads();                 // drain tile 0
  int cur = 0;
  for (int kt = 0; kt < NT; ++kt) {
    if (kt + 1 < NT) stage(cur ^ 1, kt + 1);     // issue-early (overlaps MFMA)
    const u16* As = smem + cur * 16384;
    const u16* Bs = smem + cur * 16384 + 8192;
#pragma unroll
    for (int kk = 0; kk < 2; ++kk) {
      const int lk = (kk * 32 + (lane >> 4) * 8) ^ lswz;
      bf16x8 af[4], bfv[2];
#pragma unroll
      for (int i = 0; i < 4; ++i)
        af[i] = *(const bf16x8*)&As[(wr * 64 + i * 16 + lrow) * BK + lk];
#pragma unroll
      for (int j = 0; j < 2; ++j)
        bfv[j] = *(const bf16x8*)&Bs[(wc * 32 + j * 16 + lrow) * BK + lk];
#pragma unroll
      for (int i = 0; i < 4; ++i)
#pragma unroll
        for (int j = 0; j < 2; ++j)
          acc[i][j] = __builtin_amdgcn_mfma_f32_16x16x32_bf16(af[i], bfv[j], acc[i][j], 0, 0, 0);
    }
    __syncthreads();               // wait-late: drains next tile's loads + LDS reads
    cur ^= 1;
  }

  const int lr = (lane >> 4) * 4;
  if constexpr (sizeof(OT) == 2) {
    u16* Ct = smem;                 // [128][132] bf16 = 33792 B
#pragma unroll
    for (int i = 0; i < 4; ++i)
#pragma unroll
      for (int j = 0; j < 2; ++j) {
        const int ccol = wc * 32 + j * 16 + lrow;
        float bv = 0.f;
        if constexpr (BIASMODE == 1) bv = bias[col0 + ccol];
#pragma unroll
        for (int r = 0; r < 4; ++r) {
          const int rrow = wr * 64 + i * 16 + lr + r;
          float b2 = bv;
          if constexpr (BIASMODE == 2) b2 = bias[row0 + rrow];
          Ct[rrow * 132 + ccol] = f2bf(acc[i][j][r] + b2);
        }
      }
    __syncthreads();
#pragma unroll
    for (int it = 0; it < 4; ++it) {
      const int id = it * 512 + t;
      const int row = id >> 4, c16 = (id & 15) * 8;
      *(bf16x8*)((u16*)C + (size_t)(row0 + row) * N + col0 + c16) =
          *(const bf16x8*)&Ct[row * 132 + c16];
    }
  } else {
    const int orow = row0 + wr * 64, ocol = col0 + wc * 32;
#pragma unroll
    for (int i = 0; i < 4; ++i)
#pragma unroll
      for (int j = 0; j < 2; ++j) {
        const int cc2 = ocol + j * 16 + lrow;
        float bv = 0.f;
        if constexpr (BIASMODE == 1) bv = bias[cc2];
#pragma unroll
        for (int r = 0; r < 4; ++r) {
          const int rr = orow + i * 16 + lr + r;
          float b2 = bv;
          if constexpr (BIASMODE == 2) b2 = bias[rr];
          C[(size_t)rr * N + cc2] = acc[i][j][r] + b2;
        }
      }
  }
}

// ============================================================================
// reduceG: Gbf[b][i][j] = bf16( sum_p Gpart[b][p][upper(i,j)] )  (symmetric)
// ============================================================================
__global__ __launch_bounds__(256)
void reduceG(const float* __restrict__ Gp, u16* __restrict__ Gbf) {
  const int b = blockIdx.y;
  const int e = blockIdx.x * 256 + threadIdx.x;
  const int i = e / CC, j = e % CC;
  const int ee = (i <= j) ? e : (j * CC + i);
  const float* s = Gp + (size_t)b * 4 * 147456 + ee;
  Gbf[(size_t)b * 147456 + e] =
      f2bf(s[0] + s[147456] + s[2 * 147456] + s[3 * 147456]);
}

// ============================================================================
// s_softmax: per (b,h): S = M1_h @ Uk_h^T + rank-1 terms, *N^-0.5, softmax;
// AU = attn @ Uv_h -> AUb rows (i*8+h); rbias = attn @ bv'
// ============================================================================
__global__ __launch_bounds__(256)
void s_softmax(const u16* __restrict__ M1g, const u16* __restrict__ Wf,
               const float* __restrict__ bf_, const float* __restrict__ P,
               const u16* __restrict__ UvT, u16* __restrict__ AUb,
               float* __restrict__ rbias) {
  __shared__ float Sf[48 * 52];
  __shared__ __align__(16) u16 att[48 * 56];
  const int bh = blockIdx.x, b = bh >> 3, h = bh & 7;
  const int t = threadIdx.x, wid = t >> 6, lane = t & 63;
  const int lrow = lane & 15, lkq = lane >> 4;

  if (wid < 3) {
    f32x4 acc[3] = {};
    const u16* Arow = M1g + (size_t)b * 147456 + (size_t)(h * 48 + wid * 16 + lrow) * CC;
    const u16* Brow = Wf + (size_t)(CC + h * 48) * CC;    // Uk
    for (int ks = 0; ks < 12; ++ks) {
      const int k = ks * 32 + lkq * 8;
      const bf16x8 af = *(const bf16x8*)(Arow + k);
#pragma unroll
      for (int j = 0; j < 3; ++j) {
        const bf16x8 bfr = *(const bf16x8*)(Brow + (size_t)(j * 16 + lrow) * CC + k);
        acc[j] = __builtin_amdgcn_mfma_f32_16x16x32_bf16(af, bfr, acc[j], 0, 0, 0);
      }
    }
    const int lr = lkq * 4;
#pragma unroll
    for (int j = 0; j < 3; ++j)
#pragma unroll
      for (int r = 0; r < 4; ++r)
        Sf[(wid * 16 + lr + r) * 52 + j * 16 + lrow] = acc[j][r];
  }
  __syncthreads();

  if (t < 48) {
    const float bi = bf_[h * 48 + t];
    const float pq = P[b * 768 + h * 48 + t];
    float row[48];
    float mx = -1e30f;
#pragma unroll
    for (int j = 0; j < 48; ++j) {
      const float g = bf_[CC + h * 48 + j];
      const float pk = P[b * 768 + CC + h * 48 + j];
      const float s = (Sf[t * 52 + j] + bi * pk + pq * g + 4096.f * bi * g) * 0.015625f;
      row[j] = s;
      mx = fmaxf(mx, s);
    }
    float sum = 0.f;
#pragma unroll
    for (int j = 0; j < 48; ++j) { row[j] = __expf(row[j] - mx); sum += row[j]; }
    const float inv = 1.f / sum;
    float rb = 0.f;
#pragma unroll
    for (int j = 0; j < 48; ++j) {
      const float a = row[j] * inv;
      att[t * 56 + j] = f2bf(a);
      rb += a * bf_[2 * CC + h * 48 + j];
    }
#pragma unroll
    for (int j = 48; j < 56; ++j) att[t * 56 + j] = 0;
    rbias[b * CC + t * 8 + h] = rb;
  }
  __syncthreads();

  f32x4 acc[3][6] = {};
  const u16* Vbase = UvT + h * 48;
  const bf16x8 z = {};
#pragma unroll
  for (int kk = 0; kk < 2; ++kk) {
    const int k = kk * 32 + lkq * 8;
    bf16x8 af[3];
#pragma unroll
    for (int i = 0; i < 3; ++i) {
      af[i] = *(const bf16x8*)&att[(i * 16 + lrow) * 56 + k];
      if (k >= 48) af[i] = z;
    }
#pragma unroll
    for (int ct = 0; ct < 6; ++ct) {
      const int c = wid * 96 + ct * 16 + lrow;
      bf16x8 bfr = *(const bf16x8*)(Vbase + (size_t)c * CC + k);
      if (k >= 48) bfr = z;
#pragma unroll
      for (int i = 0; i < 3; ++i)
        acc[i][ct] = __builtin_amdgcn_mfma_f32_16x16x32_bf16(af[i], bfr, acc[i][ct], 0, 0, 0);
    }
  }
  const int lr = lkq * 4;
#pragma unroll
  for (int i = 0; i < 3; ++i)
#pragma unroll
    for (int ct = 0; ct < 6; ++ct) {
      const int c = wid * 96 + ct * 16 + lrow;
#pragma unroll
      for (int r = 0; r < 4; ++r) {
        const int ii = i * 16 + lr + r;
        AUb[(size_t)b * 147456 + (size_t)(ii * 8 + h) * CC + c] = f2bf(acc[i][ct][r]);
      }
    }
}

// ============================================================================
extern "C" void kernel_launch(void* const* d_in, const int* in_sizes, int n_in,
                              void* d_out, int out_size, void* d_ws, size_t ws_size,
                              hipStream_t stream) {
  const float* x      = (const float*)d_in[0];
  const float* conv_w = (const float*)d_in[1];
  const float* conv_b = (const float*)d_in[2];
  const float* wq     = (const float*)d_in[3];
  const float* bq     = (const float*)d_in[4];
  const float* wkv    = (const float*)d_in[5];
  const float* bkv    = (const float*)d_in[6];
  const float* wp     = (const float*)d_in[7];
  const float* bp     = (const float*)d_in[8];
  float* y = (float*)d_out;

  char* ws = (char*)d_ws;
  u16*   Wf    = (u16*)(ws + 0);              //   884,736 (rows 768+ unused)
  float* bf_   = (float*)(ws + 884736);       //     4,608
  u16*   wpb   = (u16*)(ws + 889344);         //   294,912
  u16*   UvT   = (u16*)(ws + 1184256);        //   294,912
  float* sx    = (float*)(ws + 1479168);      //    24,576
  float* P     = (float*)(ws + 1503744);      //    49,152
  float* rb    = (float*)(ws + 1552896);      //    24,576
  u16*   M1g   = (u16*)(ws + 1577472);        // 4,718,592
  u16*   Gbf   = (u16*)(ws + 6296064);        // 4,718,592
  u16*   AUb   = (u16*)(ws + 11014656);       // 4,718,592
  float* Gpart = (float*)(ws + 15733248);     // 37,748,736
  u16*   wtopb = (u16*)(ws + 53481984);       //   884,736  [wq;wkv] bf16
  u16*   cwTb  = (u16*)(ws + 54366720);       //   294,912  cw^T bf16
  u16*   xb    = (u16*)(ws + 54661632);       // 50,331,648
  u16*   xbT   = (u16*)(ws + 104993280);      // 50,331,648 (dead after gram)
  u16*   R     = xbT;                         // aliases xbT
  // total ws use: 155,324,928 B

  convert_x<<<dim3(6, 32, 16), dim3(256), 0, stream>>>(x, xb, xbT);
  f32_to_bf16<<<dim3(72), dim3(256), 0, stream>>>(wp, wpb, (CC * CC) / 8);
  f32_to_bf16<<<dim3(72), dim3(256), 0, stream>>>(wq, wtopb, (CC * CC) / 8);
  f32_to_bf16<<<dim3(144), dim3(256), 0, stream>>>(wkv, wtopb + CC * CC,
                                                   (2 * CC * CC) / 8);
  transpose_cw<<<dim3(6, 6), dim3(256), 0, stream>>>(conv_w, cwTb);
  bias_fuse<<<dim3(288), dim3(256), 0, stream>>>(wq, bq, wkv, bkv, conv_b, bf_);
  // Wf[0:768] = wtop @ cw : C[o][c] = sum_m wtopb[o][m]*cwTb[c][m]
  gemm_f<u16, 0, 0, 0><<<dim3(18), dim3(512), 0, stream>>>(
      wtopb, cwTb, nullptr, Wf, 2 * CC, CC, CC, CC, 3, 6, 18,
      0, 0, 0, 0, 0);
  // UvT[c][j] = sum_m cwTb[c][m]*wkv_v[j][m]  (wkv_v = wtopb rows 768+)
  gemm_f<u16, 0, 0, 0><<<dim3(9), dim3(512), 0, stream>>>(
      cwTb, wtopb + 2 * CC * CC, nullptr, UvT, CC, CC, CC, CC, 3, 3, 9,
      0, 0, 0, 0, 0);
  colsum<<<dim3(24, 16), dim3(256), 0, stream>>>(xbT, sx);
  proj_sx<<<dim3(6, 16), dim3(128), 0, stream>>>(Wf, sx, P);
  // Gram partials (symmetric: 6 upper tiles only), split-K 4
  gemm_f<float, 0, 1><<<dim3(384), dim3(512), 0, stream>>>(
      xbT, xbT, nullptr, Gpart, CC, CC, NN, 1024, 3, 3, 24,
      (long)CC * NN, (long)CC * NN, 4L * 147456, 147456, 0);
  reduceG<<<dim3(576, 16), dim3(256), 0, stream>>>(Gpart, Gbf);
  // M1g[b] = Uq @ Gx_b
  gemm_f<u16, 0><<<dim3(144), dim3(512), 0, stream>>>(
      Wf, Gbf, nullptr, M1g, CC, CC, CC, CC, 3, 3, 9,
      0, 147456, 147456, 0, 0);
  s_softmax<<<dim3(128), dim3(256), 0, stream>>>(M1g, Wf, bf_, P, UvT, AUb, rb);
  // R[b] = AUb[b] @ xb_b^T + rbias (row-bias)
  gemm_f<u16, 2><<<dim3(1536), dim3(512), 0, stream>>>(
      AUb, xb, rb, R, CC, NN, CC, CC, 32, 3, 96,
      147456, (long)NN * CC, (long)NN * CC, 0, CC);
  // y = R @ wpb^T + bp
  gemm_f<float, 1><<<dim3(1536), dim3(512), 0, stream>>>(
      R, wpb, bp, y, BB * NN, CC, CC, CC, 3, 512, 1536,
      0, 0, 0, 0, 0);
}